// Round 9
// baseline (136.186 us; speedup 1.0000x reference)
//
#include <hip/hip_runtime.h>
#include <hip/hip_bf16.h>

// TritonDynamicAttention: blocksparse causal attention, B=2,H=16,S=2048,D=64, BLOCK=32.
// R9: load-balanced flash-decode. The (bh,qi) triangle (1..64 steps/WG) collapsed
// time-averaged occupancy to ~1.8 waves/SIMD (R2 counters). Now every 1-wave WG does
// ONE <=16-block slice of one tile (grid 5120 uniform waves); multi-slice tiles write
// (m,l,O^T) partials merged by k_merge (exact flash-decode combine, log2 domain).
// Keeps: fp16 carrier, permlane32_swap exchange, exp2+defer-max softmax, K dbuf,
// early-exit block mask, fused prep.

typedef _Float16 f16_t;
typedef f16_t  f16x8  __attribute__((ext_vector_type(8)));
typedef __fp16 fp16x2 __attribute__((ext_vector_type(2)));
typedef float  f32x4  __attribute__((ext_vector_type(4)));
typedef float  f32x16 __attribute__((ext_vector_type(16)));
typedef int    i32x4  __attribute__((ext_vector_type(4)));
typedef int    i32x2  __attribute__((ext_vector_type(2)));
typedef unsigned int u32x4 __attribute__((ext_vector_type(4)));

constexpr int Bc = 2, Hc = 16, Sc = 2048, Dc = 64;
constexpr int NB = Sc / 32;                              // 64 mask blocks per side
constexpr size_t QKV_ELEMS = (size_t)Bc * Hc * Sc * Dc;  // 4194304
constexpr float LOG2E = 1.4426950408889634f;

// workspace layout (bytes)
constexpr size_t WS_KH = 0;                        // 8 MiB f16 K
constexpr size_t WS_VT = QKV_ELEMS * 2;            // 8 MiB f16 V^T
constexpr size_t WS_BM = QKV_ELEMS * 4;            // 128 KiB block mask
constexpr size_t WS_PM = WS_BM + (1 << 20);        // partial m: 8192 slots x 32 f32
constexpr size_t WS_PL = WS_PM + (1 << 20);        // partial l
constexpr size_t WS_PO = WS_PL + (1 << 20);        // partial O^T: 8192 x 64 x 32 f32 (64MB)

__device__ inline f32x16 mfma32(f16x8 a, f16x8 b, f32x16 c) {
    return __builtin_amdgcn_mfma_f32_32x32x16_f16(a, b, c, 0, 0, 0);
}
__device__ inline float fexp2(float x) { return __builtin_amdgcn_exp2f(x); }

union UB { u32x4 u; f16x8 v; };
union PK { fp16x2 h; unsigned int u; };

#if __has_builtin(__builtin_amdgcn_permlane32_swap)
#define HAVE_PLSWAP 1
__device__ inline i32x2 plswap(unsigned int a, unsigned int b) {
    return __builtin_amdgcn_permlane32_swap((int)a, (int)b, false, false);
}
__device__ inline float xhalf_max(float x) {
    i32x2 s = plswap((unsigned int)__float_as_int(x), (unsigned int)__float_as_int(x));
    return fmaxf(__int_as_float(s[0]), __int_as_float(s[1]));
}
__device__ inline float xhalf_sum(float x) {
    i32x2 s = plswap((unsigned int)__float_as_int(x), (unsigned int)__float_as_int(x));
    return __int_as_float(s[0]) + __int_as_float(s[1]);
}
#else
#define HAVE_PLSWAP 0
__device__ inline float xhalf_max(float x) { return fmaxf(x, __shfl_xor(x, 32)); }
__device__ inline float xhalf_sum(float x) { return x + __shfl_xor(x, 32); }
#endif

// ---------- fused prep (unchanged from R8) ----------
__global__ __launch_bounds__(256) void k_prep(const float* __restrict__ K,
                                              const float* __restrict__ V,
                                              const int* __restrict__ mask,
                                              const float* __restrict__ bias,
                                              f16_t* __restrict__ kh,
                                              f16_t* __restrict__ vt,
                                              unsigned char* __restrict__ bm) {
    const int bid = blockIdx.x;
    const int t   = threadIdx.x;
    if (bid < 2048) {
        size_t i = ((size_t)bid * 256 + t) * 8;
        f32x4 a = *(const f32x4*)(K + i);
        f32x4 b = *(const f32x4*)(K + i + 4);
        float xs[8] = {a[0], a[1], a[2], a[3], b[0], b[1], b[2], b[3]};
        f16x8 h;
#pragma unroll
        for (int j = 0; j < 8; j++) h[j] = (f16_t)xs[j];
        *(f16x8*)(kh + i) = h;
    } else if (bid < 3072) {
        __shared__ f16_t tile[64 * 66];
        const int b2 = bid - 2048;
        const int bh = b2 >> 5;
        const int st = b2 & 31;
        {
            int sr = t >> 2, dseg = (t & 3) * 16;
            const float* vr = V + ((size_t)bh * Sc + (size_t)st * 64 + sr) * Dc + dseg;
#pragma unroll
            for (int c = 0; c < 4; c++) {
                f32x4 a = *(const f32x4*)(vr + c * 4);
#pragma unroll
                for (int j = 0; j < 4; j++) tile[sr * 66 + dseg + c * 4 + j] = (f16_t)a[j];
            }
        }
        __syncthreads();
        {
            int dr = t >> 2, sseg = (t & 3) * 16;
            f16x8 h0, h1;
#pragma unroll
            for (int j = 0; j < 8; j++) h0[j] = tile[(sseg + j) * 66 + dr];
#pragma unroll
            for (int j = 0; j < 8; j++) h1[j] = tile[(sseg + 8 + j) * 66 + dr];
            f16_t* outp = vt + ((size_t)bh * Dc + dr) * Sc + (size_t)st * 64 + sseg;
            *(f16x8*)outp = h0;
            *(f16x8*)(outp + 8) = h1;
        }
    } else {
        const int b3 = bid - 3072;
        const int h  = b3 >> 6;
        const int br = b3 & 63;
        float bv = bias[h];
        unsigned char* outp = bm + ((size_t)h * NB + br) * NB;
        if (bv > 0.f) {
            if (t < NB) outp[t] = 1;
            return;
        }
        int bc0 = t >> 3;
        int bc1 = 32 + bc0;
        const int* base = mask + ((size_t)h * Sc + (size_t)br * 32) * (size_t)Sc;
        const int* p0 = base + 4 * t;
        const int* p1 = base + 1024 + 4 * t;
        bool d0 = (bc0 <= br), d1 = (bc1 <= br);
        int acc0 = 0, acc1 = 0;
        if (d0) {
#pragma unroll
            for (int r = 0; r < 4; r++) {
                i32x4 vv = *(const i32x4*)(p0 + (size_t)r * Sc);
                acc0 += vv[0] + vv[1] + vv[2] + vv[3];
            }
        }
        if (d1) {
#pragma unroll
            for (int r = 0; r < 4; r++) {
                i32x4 vv = *(const i32x4*)(p1 + (size_t)r * Sc);
                acc1 += vv[0] + vv[1] + vv[2] + vv[3];
            }
        }
        int g0 = acc0, g1 = acc1;
#pragma unroll
        for (int off = 1; off < 8; off <<= 1) {
            g0 += __shfl_xor(g0, off);
            g1 += __shfl_xor(g1, off);
        }
        bool act0 = (float)g0 + bv > 0.f;
        bool act1 = (float)g1 + bv > 0.f;
        if (d0 && !act0) {
            for (int r = 4; r < 32; r++) {
                i32x4 vv = *(const i32x4*)(p0 + (size_t)r * Sc);
                acc0 += vv[0] + vv[1] + vv[2] + vv[3];
            }
            int s = acc0;
#pragma unroll
            for (int off = 1; off < 8; off <<= 1) s += __shfl_xor(s, off);
            act0 = (float)s + bv > 0.f;
        }
        if (d1 && !act1) {
            for (int r = 4; r < 32; r++) {
                i32x4 vv = *(const i32x4*)(p1 + (size_t)r * Sc);
                acc1 += vv[0] + vv[1] + vv[2] + vv[3];
            }
            int s = acc1;
#pragma unroll
            for (int off = 1; off < 8; off <<= 1) s += __shfl_xor(s, off);
            act1 = (float)s + bv > 0.f;
        }
        if ((t & 7) == 0) {
            if (d0) outp[bc0] = act0 ? 1 : 0;
            if (d1) outp[bc1] = act1 ? 1 : 0;
        }
    }
}

// ---------- k_attn: one 16-block slice per 1-wave WG ----------
#define KLOAD(KB_, kb_) do {                                                   \
    _Pragma("unroll")                                                          \
    for (int kc_ = 0; kc_ < 4; kc_++)                                          \
        KB_[kc_] = *(const f16x8*)(khp + (size_t)(((kb_) * 32 + l31) * Dc)     \
                                   + kc_ * 16 + hi * 8);                       \
} while (0)

#if HAVE_PLSWAP
#define EXCHANGE_P do {                                                        \
        i32x2 e0_ = plswap(pb_[0], pb_[2]);                                    \
        i32x2 e1_ = plswap(pb_[1], pb_[3]);                                    \
        i32x2 e2_ = plswap(pb_[4], pb_[6]);                                    \
        i32x2 e3_ = plswap(pb_[5], pb_[7]);                                    \
        b0_.u[0] = (unsigned int)e0_[0]; b0_.u[1] = (unsigned int)e1_[0];      \
        b0_.u[2] = (unsigned int)e0_[1]; b0_.u[3] = (unsigned int)e1_[1];      \
        b1_.u[0] = (unsigned int)e2_[0]; b1_.u[1] = (unsigned int)e3_[0];      \
        b1_.u[2] = (unsigned int)e2_[1]; b1_.u[3] = (unsigned int)e3_[1];      \
} while (0)
#else
#define EXCHANGE_P do {                                                        \
        unsigned int qb_[8];                                                   \
        _Pragma("unroll")                                                      \
        for (int i_ = 0; i_ < 8; i_++)                                         \
            qb_[i_] = (unsigned int)__shfl_xor((int)pb_[i_], 32);              \
        b0_.u[0] = hi ? qb_[2] : pb_[0]; b0_.u[1] = hi ? qb_[3] : pb_[1];      \
        b0_.u[2] = hi ? pb_[2] : qb_[0]; b0_.u[3] = hi ? pb_[3] : qb_[1];      \
        b1_.u[0] = hi ? qb_[6] : pb_[4]; b1_.u[1] = hi ? qb_[7] : pb_[5];      \
        b1_.u[2] = hi ? pb_[6] : qb_[4]; b1_.u[3] = hi ? pb_[7] : qb_[5];      \
} while (0)
#endif

// li_ = local step index (bit in actmask), kb_ = global block index
#define STEP(KB_, kb_, li_) do {                                               \
    if ((actmask >> (li_)) & 1ull) {                                           \
        f16x8 va_[2][2];                                                       \
        _Pragma("unroll")                                                      \
        for (int t_ = 0; t_ < 2; t_++)                                         \
            _Pragma("unroll")                                                  \
            for (int c_ = 0; c_ < 2; c_++)                                     \
                va_[t_][c_] = *(const f16x8*)(vtp + (size_t)(t_ * 32 + l31) * Sc \
                                              + (kb_) * 32 + c_ * 16 + hi * 8);   \
        f32x16 st;                                                             \
        _Pragma("unroll")                                                      \
        for (int r_ = 0; r_ < 16; r_++) st[r_] = 0.f;                          \
        _Pragma("unroll")                                                      \
        for (int kc_ = 0; kc_ < 4; kc_++)                                      \
            st = mfma32(KB_[kc_], qh[kc_], st);                                \
        if ((kb_) == brow) {                                                   \
            _Pragma("unroll")                                                  \
            for (int r_ = 0; r_ < 16; r_++) {                                  \
                int kvl_ = (r_ & 3) + 8 * (r_ >> 2) + 4 * hi;                  \
                if (kvl_ > l31) st[r_] = -1e30f;                               \
            }                                                                  \
        }                                                                      \
        float a0_ = fmaxf(fmaxf(st[0], st[1]), st[2]);                         \
        float a1_ = fmaxf(fmaxf(st[3], st[4]), st[5]);                         \
        float a2_ = fmaxf(fmaxf(st[6], st[7]), st[8]);                         \
        float a3_ = fmaxf(fmaxf(st[9], st[10]), st[11]);                       \
        float a4_ = fmaxf(fmaxf(st[12], st[13]), st[14]);                      \
        float b0m_ = fmaxf(fmaxf(a0_, a1_), a2_);                              \
        float b1m_ = fmaxf(fmaxf(a3_, a4_), st[15]);                           \
        float mx_ = xhalf_max(fmaxf(b0m_, b1m_));                              \
        if (__ballot(mx_ > mrow + 11.0f)) {                                    \
            float mn_ = fmaxf(mrow, mx_);                                      \
            float al_ = fexp2(mrow - mn_);                                     \
            mrow = mn_;                                                        \
            lrow *= al_;                                                       \
            ot0 *= al_; ot1 *= al_;                                            \
        }                                                                      \
        _Pragma("unroll")                                                      \
        for (int r_ = 0; r_ < 16; r_++) st[r_] = fexp2(st[r_] - mrow);         \
        {                                                                      \
            float s0 = (st[0] + st[1]) + (st[2] + st[3]);                      \
            float s1 = (st[4] + st[5]) + (st[6] + st[7]);                      \
            float s2 = (st[8] + st[9]) + (st[10] + st[11]);                    \
            float s3 = (st[12] + st[13]) + (st[14] + st[15]);                  \
            lrow += ((s0 + s1) + (s2 + s3));                                   \
        }                                                                      \
        unsigned int pb_[8];                                                   \
        _Pragma("unroll")                                                      \
        for (int i_ = 0; i_ < 8; i_++) {                                       \
            PK pk_;                                                            \
            pk_.h = __builtin_amdgcn_cvt_pkrtz(st[2 * i_], st[2 * i_ + 1]);    \
            pb_[i_] = pk_.u;                                                   \
        }                                                                      \
        UB b0_, b1_;                                                           \
        EXCHANGE_P;                                                            \
        ot0 = mfma32(va_[0][0], b0_.v, ot0);                                   \
        ot0 = mfma32(va_[0][1], b1_.v, ot0);                                   \
        ot1 = mfma32(va_[1][0], b0_.v, ot1);                                   \
        ot1 = mfma32(va_[1][1], b1_.v, ot1);                                   \
    }                                                                          \
} while (0)

__global__ __launch_bounds__(64, 4) void k_attn(const float* __restrict__ Q,
                                                const f16_t* __restrict__ KH,
                                                const f16_t* __restrict__ VT,
                                                const unsigned char* __restrict__ BM,
                                                float* __restrict__ pm,
                                                float* __restrict__ plv,
                                                float* __restrict__ po,
                                                float* __restrict__ Out) {
    // widx in [0,160) -> (qi, slice): qi<16: 1 slice; 16-31: 2; 32-47: 3; 48-63: 4
    const int bh   = blockIdx.x & 31;
    const int widx = blockIdx.x >> 5;
    int qi, slice, nsl;
    if (widx < 16)      { qi = widx;                 slice = 0;               nsl = 1; }
    else if (widx < 48) { qi = 16 + ((widx - 16) >> 1); slice = (widx - 16) & 1; nsl = 2; }
    else if (widx < 96) { qi = 32 + (widx - 48) / 3;    slice = (widx - 48) % 3; nsl = 3; }
    else                { qi = 48 + ((widx - 96) >> 2); slice = (widx - 96) & 3; nsl = 4; }

    const int h    = bh & (Hc - 1);
    const int lane = threadIdx.x;
    const int l31  = lane & 31, hi = lane >> 5;

    const size_t bh_off = (size_t)bh * Sc * Dc;
    const float* q_ptr  = Q  + bh_off;
    const f16_t* khp    = KH + bh_off;
    const f16_t* vtp    = VT + bh_off;

    const int q0   = qi * 32;
    const int brow = qi;
    const int kb0  = slice * 16;
    const int ns   = min(16, brow + 1 - kb0);       // steps in this slice (>=1)
    const unsigned char* bmrow = BM + ((size_t)h * NB + brow) * NB;
    const unsigned long long actmask =
        __ballot(lane < 16 && bmrow[kb0 + lane] != 0);

    // Q fragments (B-operand of S^T), pre-scaled by log2e
    f16x8 qh[4];
    {
        const float* qr = q_ptr + (size_t)(q0 + l31) * Dc + hi * 8;
#pragma unroll
        for (int kc = 0; kc < 4; kc++) {
            f32x4 a = *(const f32x4*)(qr + kc * 16);
            f32x4 b = *(const f32x4*)(qr + kc * 16 + 4);
            float xs[8] = {a[0], a[1], a[2], a[3], b[0], b[1], b[2], b[3]};
#pragma unroll
            for (int j2 = 0; j2 < 8; j2++) qh[kc][j2] = (f16_t)(xs[j2] * LOG2E);
        }
    }

    f32x16 ot0, ot1;
#pragma unroll
    for (int r = 0; r < 16; r++) { ot0[r] = 0.f; ot1[r] = 0.f; }
    float mrow = -INFINITY, lrow = 0.f;

    f16x8 kbufA[4], kbufB[4];
    KLOAD(kbufA, kb0);
    int i = 0;
    while (i < ns) {
        if (i + 1 < ns) KLOAD(kbufB, kb0 + i + 1);
        STEP(kbufA, kb0 + i, i);
        i++;
        if (i >= ns) break;
        if (i + 1 < ns) KLOAD(kbufA, kb0 + i + 1);
        STEP(kbufB, kb0 + i, i);
        i++;
    }

    float lsum = xhalf_sum(lrow);

    if (nsl == 1) {
        // single-slice tile: normalize and write output directly
        float inv = (lsum > 0.f) ? (1.f / lsum) : 0.f;
        float* op = Out + bh_off + (size_t)(q0 + l31) * Dc;
#pragma unroll
        for (int g = 0; g < 4; g++) {
            f32x4 w0, w1;
#pragma unroll
            for (int jj = 0; jj < 4; jj++) {
                int r = g * 4 + jj;
                w0[jj] = ot0[r] * inv;
                w1[jj] = ot1[r] * inv;
            }
            *(f32x4*)(op + g * 8 + hi * 4)      = w0;
            *(f32x4*)(op + 32 + g * 8 + hi * 4) = w1;
        }
    } else {
        // write partial (m, l, O^T[d][q]) for k_merge
        const size_t slot = ((size_t)bh * NB + qi) * 4 + slice;
        float* pom = po + slot * (64 * 32);
#pragma unroll
        for (int r = 0; r < 16; r++) {
            int d0 = (r & 3) + 8 * (r >> 2) + 4 * hi;
            pom[d0 * 32 + l31]        = ot0[r];
            pom[(d0 + 32) * 32 + l31] = ot1[r];
        }
        if (hi == 0) {
            pm[slot * 32 + l31]  = mrow;
            plv[slot * 32 + l31] = lsum;
        }
    }
}

// ---------- k_merge: combine 2-4 partials per tile (qi >= 16) ----------
__global__ __launch_bounds__(64) void k_merge(const float* __restrict__ pm,
                                              const float* __restrict__ plv,
                                              const float* __restrict__ po,
                                              float* __restrict__ Out) {
    const int bh = blockIdx.x & 31;
    const int qi = 16 + (blockIdx.x >> 5);           // 16..63
    const int n  = (qi + 16) >> 4;                   // 2..4 slices
    const int t  = threadIdx.x;
    const int q  = t & 31, half = t >> 5;

    const size_t base = ((size_t)bh * NB + qi) * 4;
    float m[4], l[4];
#pragma unroll
    for (int s = 0; s < 4; s++) {
        if (s < n) { m[s] = pm[(base + s) * 32 + q]; l[s] = plv[(base + s) * 32 + q]; }
        else       { m[s] = -INFINITY;               l[s] = 0.f; }
    }
    float mm = fmaxf(fmaxf(m[0], m[1]), fmaxf(m[2], m[3]));
    float a[4];
    float lt = 0.f;
#pragma unroll
    for (int s = 0; s < 4; s++) {
        a[s] = (m[s] > -1e37f) ? fexp2(m[s] - mm) : 0.f;
        lt += a[s] * l[s];
    }
    float inv = (lt > 0.f) ? (1.f / lt) : 0.f;

    float* op = Out + ((size_t)bh * Sc + (size_t)qi * 32 + q) * Dc + half * 32;
#pragma unroll
    for (int g = 0; g < 8; g++) {          // 8 groups of 4 d
        f32x4 w;
#pragma unroll
        for (int jj = 0; jj < 4; jj++) {
            int d = half * 32 + g * 4 + jj;
            float acc = 0.f;
#pragma unroll
            for (int s = 0; s < 4; s++) {
                if (s < n) acc += a[s] * po[(base + s) * (64 * 32) + d * 32 + q];
            }
            w[jj] = acc * inv;
        }
        *(f32x4*)(op + g * 4) = w;
    }
}

extern "C" void kernel_launch(void* const* d_in, const int* in_sizes, int n_in,
                              void* d_out, int out_size, void* d_ws, size_t ws_size,
                              hipStream_t stream) {
    const float* Q    = (const float*)d_in[0];
    const float* K    = (const float*)d_in[1];
    const float* V    = (const float*)d_in[2];
    const float* bias = (const float*)d_in[3];
    const int*   mask = (const int*)d_in[4];
    float* out = (float*)d_out;

    char* ws = (char*)d_ws;
    f16_t* kh = (f16_t*)(ws + WS_KH);
    f16_t* vt = (f16_t*)(ws + WS_VT);
    unsigned char* bm = (unsigned char*)(ws + WS_BM);
    float* pm  = (float*)(ws + WS_PM);
    float* plv = (float*)(ws + WS_PL);
    float* po  = (float*)(ws + WS_PO);

    k_prep  <<<4096,     256, 0, stream>>>(K, V, mask, bias, kh, vt, bm);
    k_attn  <<<32 * 160, 64,  0, stream>>>(Q, kh, vt, bm, pm, plv, po, out);
    k_merge <<<32 * 48,  64,  0, stream>>>(pm, plv, po, out);
}

// Round 11
// 116.581 us; speedup vs baseline: 1.1682x; 1.1682x over previous
//
#include <hip/hip_runtime.h>
#include <hip/hip_bf16.h>

// TritonDynamicAttention: blocksparse causal attention, B=2,H=16,S=2048,D=64, BLOCK=32.
// R11 = R10 with the eager-exp2 init bug fixed: FIRST active step per wave takes the
// classic path (mrow = mx, then exp2) -- a stale mrow=0 above the true row max made
// subnormal-f16 P flush to zero (single-entry causal rows -> output 0 vs V[row]).
// Steps >= 2 stay eager (exp2 off the max-tree critical path; rare fire corrects by al).
// Keeps: fp16 carrier, kv-parity 2-wave split + exact LDS merge, permlane32_swap,
// cvt_pkrtz, K dbuf, early-exit block mask, fused prep, R4 bid mapping.

typedef _Float16 f16_t;
typedef f16_t  f16x8  __attribute__((ext_vector_type(8)));
typedef __fp16 fp16x2 __attribute__((ext_vector_type(2)));
typedef float  f32x4  __attribute__((ext_vector_type(4)));
typedef float  f32x16 __attribute__((ext_vector_type(16)));
typedef int    i32x4  __attribute__((ext_vector_type(4)));
typedef int    i32x2  __attribute__((ext_vector_type(2)));
typedef unsigned int u32x4 __attribute__((ext_vector_type(4)));

constexpr int Bc = 2, Hc = 16, Sc = 2048, Dc = 64;
constexpr int NB = Sc / 32;                              // 64 mask blocks per side
constexpr size_t QKV_ELEMS = (size_t)Bc * Hc * Sc * Dc;  // 4194304
constexpr float LOG2E = 1.4426950408889634f;

__device__ inline f32x16 mfma32(f16x8 a, f16x8 b, f32x16 c) {
    return __builtin_amdgcn_mfma_f32_32x32x16_f16(a, b, c, 0, 0, 0);
}
__device__ inline float fexp2(float x) { return __builtin_amdgcn_exp2f(x); }

union UB { u32x4 u; f16x8 v; };
union PK { fp16x2 h; unsigned int u; };

#if __has_builtin(__builtin_amdgcn_permlane32_swap)
#define HAVE_PLSWAP 1
__device__ inline i32x2 plswap(unsigned int a, unsigned int b) {
    return __builtin_amdgcn_permlane32_swap((int)a, (int)b, false, false);
}
__device__ inline float xhalf_max(float x) {
    i32x2 s = plswap((unsigned int)__float_as_int(x), (unsigned int)__float_as_int(x));
    return fmaxf(__int_as_float(s[0]), __int_as_float(s[1]));
}
__device__ inline float xhalf_sum(float x) {
    i32x2 s = plswap((unsigned int)__float_as_int(x), (unsigned int)__float_as_int(x));
    return __int_as_float(s[0]) + __int_as_float(s[1]);
}
#else
#define HAVE_PLSWAP 0
__device__ inline float xhalf_max(float x) { return fmaxf(x, __shfl_xor(x, 32)); }
__device__ inline float xhalf_sum(float x) { return x + __shfl_xor(x, 32); }
#endif

// ---------- fused prep: [0,2048) K->f16 | [2048,3072) V^T f16 | [3072,4096) blockmask --
__global__ __launch_bounds__(256) void k_prep(const float* __restrict__ K,
                                              const float* __restrict__ V,
                                              const int* __restrict__ mask,
                                              const float* __restrict__ bias,
                                              f16_t* __restrict__ kh,
                                              f16_t* __restrict__ vt,
                                              unsigned char* __restrict__ bm) {
    const int bid = blockIdx.x;
    const int t   = threadIdx.x;
    if (bid < 2048) {
        size_t i = ((size_t)bid * 256 + t) * 8;
        f32x4 a = *(const f32x4*)(K + i);
        f32x4 b = *(const f32x4*)(K + i + 4);
        float xs[8] = {a[0], a[1], a[2], a[3], b[0], b[1], b[2], b[3]};
        f16x8 h;
#pragma unroll
        for (int j = 0; j < 8; j++) h[j] = (f16_t)xs[j];
        *(f16x8*)(kh + i) = h;
    } else if (bid < 3072) {
        __shared__ f16_t tile[64 * 66];
        const int b2 = bid - 2048;
        const int bh = b2 >> 5;
        const int st = b2 & 31;
        {
            int sr = t >> 2, dseg = (t & 3) * 16;
            const float* vr = V + ((size_t)bh * Sc + (size_t)st * 64 + sr) * Dc + dseg;
#pragma unroll
            for (int c = 0; c < 4; c++) {
                f32x4 a = *(const f32x4*)(vr + c * 4);
#pragma unroll
                for (int j = 0; j < 4; j++) tile[sr * 66 + dseg + c * 4 + j] = (f16_t)a[j];
            }
        }
        __syncthreads();
        {
            int dr = t >> 2, sseg = (t & 3) * 16;
            f16x8 h0, h1;
#pragma unroll
            for (int j = 0; j < 8; j++) h0[j] = tile[(sseg + j) * 66 + dr];
#pragma unroll
            for (int j = 0; j < 8; j++) h1[j] = tile[(sseg + 8 + j) * 66 + dr];
            f16_t* outp = vt + ((size_t)bh * Dc + dr) * Sc + (size_t)st * 64 + sseg;
            *(f16x8*)outp = h0;
            *(f16x8*)(outp + 8) = h1;
        }
    } else {
        const int b3 = bid - 3072;
        const int h  = b3 >> 6;
        const int br = b3 & 63;
        float bv = bias[h];
        unsigned char* outp = bm + ((size_t)h * NB + br) * NB;
        if (bv > 0.f) {
            if (t < NB) outp[t] = 1;
            return;
        }
        int bc0 = t >> 3;
        int bc1 = 32 + bc0;
        const int* base = mask + ((size_t)h * Sc + (size_t)br * 32) * (size_t)Sc;
        const int* p0 = base + 4 * t;
        const int* p1 = base + 1024 + 4 * t;
        bool d0 = (bc0 <= br), d1 = (bc1 <= br);
        int acc0 = 0, acc1 = 0;
        if (d0) {
#pragma unroll
            for (int r = 0; r < 4; r++) {
                i32x4 vv = *(const i32x4*)(p0 + (size_t)r * Sc);
                acc0 += vv[0] + vv[1] + vv[2] + vv[3];
            }
        }
        if (d1) {
#pragma unroll
            for (int r = 0; r < 4; r++) {
                i32x4 vv = *(const i32x4*)(p1 + (size_t)r * Sc);
                acc1 += vv[0] + vv[1] + vv[2] + vv[3];
            }
        }
        int g0 = acc0, g1 = acc1;
#pragma unroll
        for (int off = 1; off < 8; off <<= 1) {
            g0 += __shfl_xor(g0, off);
            g1 += __shfl_xor(g1, off);
        }
        bool act0 = (float)g0 + bv > 0.f;   // certified active (remaining rows >= 0)
        bool act1 = (float)g1 + bv > 0.f;
        if (d0 && !act0) {
            for (int r = 4; r < 32; r++) {
                i32x4 vv = *(const i32x4*)(p0 + (size_t)r * Sc);
                acc0 += vv[0] + vv[1] + vv[2] + vv[3];
            }
            int s = acc0;
#pragma unroll
            for (int off = 1; off < 8; off <<= 1) s += __shfl_xor(s, off);
            act0 = (float)s + bv > 0.f;
        }
        if (d1 && !act1) {
            for (int r = 4; r < 32; r++) {
                i32x4 vv = *(const i32x4*)(p1 + (size_t)r * Sc);
                acc1 += vv[0] + vv[1] + vv[2] + vv[3];
            }
            int s = acc1;
#pragma unroll
            for (int off = 1; off < 8; off <<= 1) s += __shfl_xor(s, off);
            act1 = (float)s + bv > 0.f;
        }
        if ((t & 7) == 0) {
            if (d0) outp[bc0] = act0 ? 1 : 0;
            if (d1) outp[bc1] = act1 ? 1 : 0;
        }
    }
}

// ---------- flash blocksparse causal attention, 32x32 swapped, fp16, parity split ------
#define KLOAD(KB_, kb_) do {                                                   \
    _Pragma("unroll")                                                          \
    for (int kc_ = 0; kc_ < 4; kc_++)                                          \
        KB_[kc_] = *(const f16x8*)(khp + (size_t)(((kb_) * 32 + l31) * Dc)     \
                                   + kc_ * 16 + hi * 8);                       \
} while (0)

#if HAVE_PLSWAP
#define EXCHANGE_P do {                                                        \
        i32x2 e0_ = plswap(pb_[0], pb_[2]);                                    \
        i32x2 e1_ = plswap(pb_[1], pb_[3]);                                    \
        i32x2 e2_ = plswap(pb_[4], pb_[6]);                                    \
        i32x2 e3_ = plswap(pb_[5], pb_[7]);                                    \
        b0_.u[0] = (unsigned int)e0_[0]; b0_.u[1] = (unsigned int)e1_[0];      \
        b0_.u[2] = (unsigned int)e0_[1]; b0_.u[3] = (unsigned int)e1_[1];      \
        b1_.u[0] = (unsigned int)e2_[0]; b1_.u[1] = (unsigned int)e3_[0];      \
        b1_.u[2] = (unsigned int)e2_[1]; b1_.u[3] = (unsigned int)e3_[1];      \
} while (0)
#else
#define EXCHANGE_P do {                                                        \
        unsigned int qb_[8];                                                   \
        _Pragma("unroll")                                                      \
        for (int i_ = 0; i_ < 8; i_++)                                         \
            qb_[i_] = (unsigned int)__shfl_xor((int)pb_[i_], 32);              \
        b0_.u[0] = hi ? qb_[2] : pb_[0]; b0_.u[1] = hi ? qb_[3] : pb_[1];      \
        b0_.u[2] = hi ? pb_[2] : qb_[0]; b0_.u[3] = hi ? pb_[3] : qb_[1];      \
        b1_.u[0] = hi ? qb_[6] : pb_[4]; b1_.u[1] = hi ? qb_[7] : pb_[5];      \
        b1_.u[2] = hi ? pb_[6] : qb_[4]; b1_.u[3] = hi ? pb_[7] : qb_[5];      \
} while (0)
#endif

// First active step: classic (mrow = mx, then exp2). Later steps: eager exp2 with
// old mrow (off the max-tree path); rare fire corrects p/lrow/ot by al (exact).
#define STEP(KB_, kb_) do {                                                    \
    if ((actmask >> (kb_)) & 1ull) {                                           \
        f16x8 va_[2][2];                                                       \
        _Pragma("unroll")                                                      \
        for (int t_ = 0; t_ < 2; t_++)                                         \
            _Pragma("unroll")                                                  \
            for (int c_ = 0; c_ < 2; c_++)                                     \
                va_[t_][c_] = *(const f16x8*)(vtp + (size_t)(t_ * 32 + l31) * Sc \
                                              + (kb_) * 32 + c_ * 16 + hi * 8);   \
        f32x16 st;                                                             \
        _Pragma("unroll")                                                      \
        for (int r_ = 0; r_ < 16; r_++) st[r_] = 0.f;                          \
        _Pragma("unroll")                                                      \
        for (int kc_ = 0; kc_ < 4; kc_++)                                      \
            st = mfma32(KB_[kc_], qh[kc_], st);                                \
        if ((kb_) == brow) {                                                   \
            _Pragma("unroll")                                                  \
            for (int r_ = 0; r_ < 16; r_++) {                                  \
                int kvl_ = (r_ & 3) + 8 * (r_ >> 2) + 4 * hi;                  \
                if (kvl_ > l31) st[r_] = -1e30f;                               \
            }                                                                  \
        }                                                                      \
        float a0_ = fmaxf(fmaxf(st[0], st[1]), st[2]);                         \
        float a1_ = fmaxf(fmaxf(st[3], st[4]), st[5]);                         \
        float a2_ = fmaxf(fmaxf(st[6], st[7]), st[8]);                         \
        float a3_ = fmaxf(fmaxf(st[9], st[10]), st[11]);                       \
        float a4_ = fmaxf(fmaxf(st[12], st[13]), st[14]);                      \
        float b0m_ = fmaxf(fmaxf(a0_, a1_), a2_);                              \
        float b1m_ = fmaxf(fmaxf(a3_, a4_), st[15]);                           \
        float mx_ = xhalf_max(fmaxf(b0m_, b1m_));                              \
        if (!started) {                                                        \
            started = true;                                                    \
            mrow = mx_;                                                        \
            _Pragma("unroll")                                                  \
            for (int r_ = 0; r_ < 16; r_++) st[r_] = fexp2(st[r_] - mrow);     \
        } else {                                                               \
            _Pragma("unroll")                                                  \
            for (int r_ = 0; r_ < 16; r_++) st[r_] = fexp2(st[r_] - mrow);     \
            if (__ballot(mx_ > mrow + 11.0f)) {                                \
                float mn_ = fmaxf(mrow, mx_);                                  \
                float al_ = fexp2(mrow - mn_);                                 \
                mrow = mn_;                                                    \
                lrow *= al_;                                                   \
                ot0 *= al_; ot1 *= al_;                                        \
                _Pragma("unroll")                                              \
                for (int r_ = 0; r_ < 16; r_++) st[r_] *= al_;                 \
            }                                                                  \
        }                                                                      \
        {                                                                      \
            float s0 = (st[0] + st[1]) + (st[2] + st[3]);                      \
            float s1 = (st[4] + st[5]) + (st[6] + st[7]);                      \
            float s2 = (st[8] + st[9]) + (st[10] + st[11]);                    \
            float s3 = (st[12] + st[13]) + (st[14] + st[15]);                  \
            lrow += ((s0 + s1) + (s2 + s3));                                   \
        }                                                                      \
        unsigned int pb_[8];                                                   \
        _Pragma("unroll")                                                      \
        for (int i_ = 0; i_ < 8; i_++) {                                       \
            PK pk_;                                                            \
            pk_.h = __builtin_amdgcn_cvt_pkrtz(st[2 * i_], st[2 * i_ + 1]);    \
            pb_[i_] = pk_.u;                                                   \
        }                                                                      \
        UB b0_, b1_;                                                           \
        EXCHANGE_P;                                                            \
        ot0 = mfma32(va_[0][0], b0_.v, ot0);                                   \
        ot0 = mfma32(va_[0][1], b1_.v, ot0);                                   \
        ot1 = mfma32(va_[1][0], b0_.v, ot1);                                   \
        ot1 = mfma32(va_[1][1], b1_.v, ot1);                                   \
    }                                                                          \
} while (0)

__global__ __launch_bounds__(128, 4) void k_attn(const float* __restrict__ Q,
                                                 const f16_t* __restrict__ KH,
                                                 const f16_t* __restrict__ VT,
                                                 const unsigned char* __restrict__ BM,
                                                 float* __restrict__ Out) {
    __shared__ float lds_o[64 * 33];
    __shared__ float lds_m[32];
    __shared__ float lds_l[32];

    const int qi   = 63 - (int)(blockIdx.x >> 5);   // heavy block-rows dispatch first
    const int bh   = blockIdx.x & 31;
    const int h    = bh & (Hc - 1);
    const int w    = threadIdx.x >> 6;
    const int lane = threadIdx.x & 63;
    const int l31  = lane & 31, hi = lane >> 5;

    const size_t bh_off = (size_t)bh * Sc * Dc;
    const float* q_ptr  = Q  + bh_off;
    const f16_t* khp    = KH + bh_off;
    const f16_t* vtp    = VT + bh_off;

    const int q0   = qi * 32;
    const int brow = qi;
    const unsigned char* bmrow = BM + ((size_t)h * NB + brow) * NB;
    const unsigned long long actmask = __ballot(bmrow[lane] != 0);

    // Q fragments (B-operand of S^T), pre-scaled by log2e for exp2 softmax
    f16x8 qh[4];
    {
        const float* qr = q_ptr + (size_t)(q0 + l31) * Dc + hi * 8;
#pragma unroll
        for (int kc = 0; kc < 4; kc++) {
            f32x4 a = *(const f32x4*)(qr + kc * 16);
            f32x4 b = *(const f32x4*)(qr + kc * 16 + 4);
            float xs[8] = {a[0], a[1], a[2], a[3], b[0], b[1], b[2], b[3]};
#pragma unroll
            for (int j2 = 0; j2 < 8; j2++) qh[kc][j2] = (f16_t)(xs[j2] * LOG2E);
        }
    }

    f32x16 ot0, ot1;
#pragma unroll
    for (int r = 0; r < 16; r++) { ot0[r] = 0.f; ot1[r] = 0.f; }
    float mrow = -1e30f, lrow = 0.f;
    bool started = false;

    // this wave handles kb == w (mod 2), double-buffered
    f16x8 kbufA[4], kbufB[4];
    int ib = w;
    if (ib <= brow) KLOAD(kbufA, ib);
    while (ib <= brow) {
        if (ib + 2 <= brow) KLOAD(kbufB, ib + 2);
        STEP(kbufA, ib);
        ib += 2;
        if (ib > brow) break;
        if (ib + 2 <= brow) KLOAD(kbufA, ib + 2);
        STEP(kbufB, ib);
        ib += 2;
    }

    // ---- merge the two waves' partials (exact flash-decode merge, log2 domain) ----
    float lsum = xhalf_sum(lrow);
    if (w == 1) {
#pragma unroll
        for (int r = 0; r < 16; r++) {
            int d0 = (r & 3) + 8 * (r >> 2) + 4 * hi;
            lds_o[d0 * 33 + l31]        = ot0[r];
            lds_o[(d0 + 32) * 33 + l31] = ot1[r];
        }
        if (hi == 0) { lds_m[l31] = mrow; lds_l[l31] = lsum; }
    }
    __syncthreads();
    if (w == 0) {
        float m1 = lds_m[l31], l1 = lds_l[l31];
        float mm = fmaxf(mrow, m1);
        float a0 = (mrow > -1e29f) ? fexp2(mrow - mm) : 0.f;
        float a1 = (m1   > -1e29f) ? fexp2(m1   - mm) : 0.f;
        float lt = lsum * a0 + l1 * a1;
        float inv = (lt > 0.f) ? (1.f / lt) : 0.f;
        float* op = Out + bh_off + (size_t)(q0 + l31) * Dc;
#pragma unroll
        for (int g = 0; g < 4; g++) {
            f32x4 w0, w1;
#pragma unroll
            for (int jj = 0; jj < 4; jj++) {
                int r = g * 4 + jj;
                int d0 = jj + 8 * g + 4 * hi;
                w0[jj] = (ot0[r] * a0 + lds_o[d0 * 33 + l31] * a1) * inv;
                w1[jj] = (ot1[r] * a0 + lds_o[(d0 + 32) * 33 + l31] * a1) * inv;
            }
            *(f32x4*)(op + g * 8 + hi * 4)      = w0;
            *(f32x4*)(op + 32 + g * 8 + hi * 4) = w1;
        }
    }
}

extern "C" void kernel_launch(void* const* d_in, const int* in_sizes, int n_in,
                              void* d_out, int out_size, void* d_ws, size_t ws_size,
                              hipStream_t stream) {
    const float* Q    = (const float*)d_in[0];
    const float* K    = (const float*)d_in[1];
    const float* V    = (const float*)d_in[2];
    const float* bias = (const float*)d_in[3];
    const int*   mask = (const int*)d_in[4];
    float* out = (float*)d_out;

    char* ws = (char*)d_ws;
    f16_t* kh = (f16_t*)ws;                                    // 8 MiB
    f16_t* vt = (f16_t*)(ws + QKV_ELEMS * 2);                  // 8 MiB
    unsigned char* bm = (unsigned char*)(ws + QKV_ELEMS * 4);  // 64 KiB

    k_prep <<<4096, 256, 0, stream>>>(K, V, mask, bias, kh, vt, bm);
    k_attn <<<Bc * Hc * NB, 128, 0, stream>>>(Q, kh, vt, bm, out);
}

// Round 12
// 86.540 us; speedup vs baseline: 1.5737x; 1.3471x over previous
//
#include <hip/hip_runtime.h>
#include <hip/hip_bf16.h>

// TritonDynamicAttention: blocksparse causal attention, B=2,H=16,S=2048,D=64, BLOCK=32.
// R12 = R8 with the K double-buffer REMOVED to push live VGPRs safely under the 128
// hard cap of __launch_bounds__(128,4). Register tally at R8 (~132) suggests the
// inner loop was spilling to scratch -- explaining why wall time (~90us k_attn) is
// ~4x the latency-chain model (65 steps/SIMD x ~875cy / 4-wave overlap). K/V are
// L2-resident (~2MB/XCD), so un-dbuf'd loads are covered by 4-wave TLP once real.
// STEP reverted to R8 classic (max -> exp2); no eager, no 'started' temps.
// Keeps: fp16 carrier, kv-parity 2-wave split + exact LDS merge, permlane32_swap,
// cvt_pkrtz, exp2 w/ log2e-folded Q, defer-max, early-exit mask, fused prep.

typedef _Float16 f16_t;
typedef f16_t  f16x8  __attribute__((ext_vector_type(8)));
typedef __fp16 fp16x2 __attribute__((ext_vector_type(2)));
typedef float  f32x4  __attribute__((ext_vector_type(4)));
typedef float  f32x16 __attribute__((ext_vector_type(16)));
typedef int    i32x4  __attribute__((ext_vector_type(4)));
typedef int    i32x2  __attribute__((ext_vector_type(2)));
typedef unsigned int u32x4 __attribute__((ext_vector_type(4)));

constexpr int Bc = 2, Hc = 16, Sc = 2048, Dc = 64;
constexpr int NB = Sc / 32;                              // 64 mask blocks per side
constexpr size_t QKV_ELEMS = (size_t)Bc * Hc * Sc * Dc;  // 4194304
constexpr float LOG2E = 1.4426950408889634f;

__device__ inline f32x16 mfma32(f16x8 a, f16x8 b, f32x16 c) {
    return __builtin_amdgcn_mfma_f32_32x32x16_f16(a, b, c, 0, 0, 0);
}
__device__ inline float fexp2(float x) { return __builtin_amdgcn_exp2f(x); }

union UB { u32x4 u; f16x8 v; };
union PK { fp16x2 h; unsigned int u; };

#if __has_builtin(__builtin_amdgcn_permlane32_swap)
#define HAVE_PLSWAP 1
__device__ inline i32x2 plswap(unsigned int a, unsigned int b) {
    return __builtin_amdgcn_permlane32_swap((int)a, (int)b, false, false);
}
__device__ inline float xhalf_max(float x) {
    i32x2 s = plswap((unsigned int)__float_as_int(x), (unsigned int)__float_as_int(x));
    return fmaxf(__int_as_float(s[0]), __int_as_float(s[1]));
}
__device__ inline float xhalf_sum(float x) {
    i32x2 s = plswap((unsigned int)__float_as_int(x), (unsigned int)__float_as_int(x));
    return __int_as_float(s[0]) + __int_as_float(s[1]);
}
#else
#define HAVE_PLSWAP 0
__device__ inline float xhalf_max(float x) { return fmaxf(x, __shfl_xor(x, 32)); }
__device__ inline float xhalf_sum(float x) { return x + __shfl_xor(x, 32); }
#endif

// ---------- fused prep: [0,2048) K->f16 | [2048,3072) V^T f16 | [3072,4096) blockmask --
__global__ __launch_bounds__(256) void k_prep(const float* __restrict__ K,
                                              const float* __restrict__ V,
                                              const int* __restrict__ mask,
                                              const float* __restrict__ bias,
                                              f16_t* __restrict__ kh,
                                              f16_t* __restrict__ vt,
                                              unsigned char* __restrict__ bm) {
    const int bid = blockIdx.x;
    const int t   = threadIdx.x;
    if (bid < 2048) {
        size_t i = ((size_t)bid * 256 + t) * 8;
        f32x4 a = *(const f32x4*)(K + i);
        f32x4 b = *(const f32x4*)(K + i + 4);
        float xs[8] = {a[0], a[1], a[2], a[3], b[0], b[1], b[2], b[3]};
        f16x8 h;
#pragma unroll
        for (int j = 0; j < 8; j++) h[j] = (f16_t)xs[j];
        *(f16x8*)(kh + i) = h;
    } else if (bid < 3072) {
        __shared__ f16_t tile[64 * 66];
        const int b2 = bid - 2048;
        const int bh = b2 >> 5;
        const int st = b2 & 31;
        {
            int sr = t >> 2, dseg = (t & 3) * 16;
            const float* vr = V + ((size_t)bh * Sc + (size_t)st * 64 + sr) * Dc + dseg;
#pragma unroll
            for (int c = 0; c < 4; c++) {
                f32x4 a = *(const f32x4*)(vr + c * 4);
#pragma unroll
                for (int j = 0; j < 4; j++) tile[sr * 66 + dseg + c * 4 + j] = (f16_t)a[j];
            }
        }
        __syncthreads();
        {
            int dr = t >> 2, sseg = (t & 3) * 16;
            f16x8 h0, h1;
#pragma unroll
            for (int j = 0; j < 8; j++) h0[j] = tile[(sseg + j) * 66 + dr];
#pragma unroll
            for (int j = 0; j < 8; j++) h1[j] = tile[(sseg + 8 + j) * 66 + dr];
            f16_t* outp = vt + ((size_t)bh * Dc + dr) * Sc + (size_t)st * 64 + sseg;
            *(f16x8*)outp = h0;
            *(f16x8*)(outp + 8) = h1;
        }
    } else {
        const int b3 = bid - 3072;
        const int h  = b3 >> 6;
        const int br = b3 & 63;
        float bv = bias[h];
        unsigned char* outp = bm + ((size_t)h * NB + br) * NB;
        if (bv > 0.f) {
            if (t < NB) outp[t] = 1;
            return;
        }
        int bc0 = t >> 3;
        int bc1 = 32 + bc0;
        const int* base = mask + ((size_t)h * Sc + (size_t)br * 32) * (size_t)Sc;
        const int* p0 = base + 4 * t;
        const int* p1 = base + 1024 + 4 * t;
        bool d0 = (bc0 <= br), d1 = (bc1 <= br);
        int acc0 = 0, acc1 = 0;
        if (d0) {
#pragma unroll
            for (int r = 0; r < 4; r++) {
                i32x4 vv = *(const i32x4*)(p0 + (size_t)r * Sc);
                acc0 += vv[0] + vv[1] + vv[2] + vv[3];
            }
        }
        if (d1) {
#pragma unroll
            for (int r = 0; r < 4; r++) {
                i32x4 vv = *(const i32x4*)(p1 + (size_t)r * Sc);
                acc1 += vv[0] + vv[1] + vv[2] + vv[3];
            }
        }
        int g0 = acc0, g1 = acc1;
#pragma unroll
        for (int off = 1; off < 8; off <<= 1) {
            g0 += __shfl_xor(g0, off);
            g1 += __shfl_xor(g1, off);
        }
        bool act0 = (float)g0 + bv > 0.f;   // certified active (remaining rows >= 0)
        bool act1 = (float)g1 + bv > 0.f;
        if (d0 && !act0) {
            for (int r = 4; r < 32; r++) {
                i32x4 vv = *(const i32x4*)(p0 + (size_t)r * Sc);
                acc0 += vv[0] + vv[1] + vv[2] + vv[3];
            }
            int s = acc0;
#pragma unroll
            for (int off = 1; off < 8; off <<= 1) s += __shfl_xor(s, off);
            act0 = (float)s + bv > 0.f;
        }
        if (d1 && !act1) {
            for (int r = 4; r < 32; r++) {
                i32x4 vv = *(const i32x4*)(p1 + (size_t)r * Sc);
                acc1 += vv[0] + vv[1] + vv[2] + vv[3];
            }
            int s = acc1;
#pragma unroll
            for (int off = 1; off < 8; off <<= 1) s += __shfl_xor(s, off);
            act1 = (float)s + bv > 0.f;
        }
        if ((t & 7) == 0) {
            if (d0) outp[bc0] = act0 ? 1 : 0;
            if (d1) outp[bc1] = act1 ? 1 : 0;
        }
    }
}

// ---------- flash blocksparse causal attention, 32x32 swapped, fp16, parity split ------
#if HAVE_PLSWAP
#define EXCHANGE_P do {                                                        \
        i32x2 e0_ = plswap(pb_[0], pb_[2]);                                    \
        i32x2 e1_ = plswap(pb_[1], pb_[3]);                                    \
        i32x2 e2_ = plswap(pb_[4], pb_[6]);                                    \
        i32x2 e3_ = plswap(pb_[5], pb_[7]);                                    \
        b0_.u[0] = (unsigned int)e0_[0]; b0_.u[1] = (unsigned int)e1_[0];      \
        b0_.u[2] = (unsigned int)e0_[1]; b0_.u[3] = (unsigned int)e1_[1];      \
        b1_.u[0] = (unsigned int)e2_[0]; b1_.u[1] = (unsigned int)e3_[0];      \
        b1_.u[2] = (unsigned int)e2_[1]; b1_.u[3] = (unsigned int)e3_[1];      \
} while (0)
#else
#define EXCHANGE_P do {                                                        \
        unsigned int qb_[8];                                                   \
        _Pragma("unroll")                                                      \
        for (int i_ = 0; i_ < 8; i_++)                                         \
            qb_[i_] = (unsigned int)__shfl_xor((int)pb_[i_], 32);              \
        b0_.u[0] = hi ? qb_[2] : pb_[0]; b0_.u[1] = hi ? qb_[3] : pb_[1];      \
        b0_.u[2] = hi ? pb_[2] : qb_[0]; b0_.u[3] = hi ? pb_[3] : qb_[1];      \
        b1_.u[0] = hi ? qb_[6] : pb_[4]; b1_.u[1] = hi ? qb_[7] : pb_[5];      \
        b1_.u[2] = hi ? pb_[6] : qb_[4]; b1_.u[3] = hi ? pb_[7] : qb_[5];      \
} while (0)
#endif

// Single-buffer STEP: K and V issued together at top of the active branch; QK waits
// on K only (compiler-inserted vmcnt), PV on V. L2-resident -> TLP covers latency.
#define STEP(kb_) do {                                                         \
    if ((actmask >> (kb_)) & 1ull) {                                           \
        f16x8 kbuf_[4];                                                        \
        _Pragma("unroll")                                                      \
        for (int kc_ = 0; kc_ < 4; kc_++)                                      \
            kbuf_[kc_] = *(const f16x8*)(khp + (size_t)(((kb_) * 32 + l31) * Dc) \
                                         + kc_ * 16 + hi * 8);                 \
        f16x8 va_[2][2];                                                       \
        _Pragma("unroll")                                                      \
        for (int t_ = 0; t_ < 2; t_++)                                         \
            _Pragma("unroll")                                                  \
            for (int c_ = 0; c_ < 2; c_++)                                     \
                va_[t_][c_] = *(const f16x8*)(vtp + (size_t)(t_ * 32 + l31) * Sc \
                                              + (kb_) * 32 + c_ * 16 + hi * 8);   \
        f32x16 st;                                                             \
        _Pragma("unroll")                                                      \
        for (int r_ = 0; r_ < 16; r_++) st[r_] = 0.f;                          \
        _Pragma("unroll")                                                      \
        for (int kc_ = 0; kc_ < 4; kc_++)                                      \
            st = mfma32(kbuf_[kc_], qh[kc_], st);                              \
        if ((kb_) == brow) {                                                   \
            _Pragma("unroll")                                                  \
            for (int r_ = 0; r_ < 16; r_++) {                                  \
                int kvl_ = (r_ & 3) + 8 * (r_ >> 2) + 4 * hi;                  \
                if (kvl_ > l31) st[r_] = -1e30f;                               \
            }                                                                  \
        }                                                                      \
        float a0_ = fmaxf(fmaxf(st[0], st[1]), st[2]);                         \
        float a1_ = fmaxf(fmaxf(st[3], st[4]), st[5]);                         \
        float a2_ = fmaxf(fmaxf(st[6], st[7]), st[8]);                         \
        float a3_ = fmaxf(fmaxf(st[9], st[10]), st[11]);                       \
        float a4_ = fmaxf(fmaxf(st[12], st[13]), st[14]);                      \
        float b0m_ = fmaxf(fmaxf(a0_, a1_), a2_);                              \
        float b1m_ = fmaxf(fmaxf(a3_, a4_), st[15]);                           \
        float mx_ = xhalf_max(fmaxf(b0m_, b1m_));                              \
        if (__ballot(mx_ > mrow + 11.0f)) {                                    \
            float mn_ = fmaxf(mrow, mx_);                                      \
            float al_ = fexp2(mrow - mn_);                                     \
            mrow = mn_;                                                        \
            lrow *= al_;                                                       \
            ot0 *= al_; ot1 *= al_;                                            \
        }                                                                      \
        _Pragma("unroll")                                                      \
        for (int r_ = 0; r_ < 16; r_++) st[r_] = fexp2(st[r_] - mrow);         \
        {                                                                      \
            float s0 = (st[0] + st[1]) + (st[2] + st[3]);                      \
            float s1 = (st[4] + st[5]) + (st[6] + st[7]);                      \
            float s2 = (st[8] + st[9]) + (st[10] + st[11]);                    \
            float s3 = (st[12] + st[13]) + (st[14] + st[15]);                  \
            lrow += ((s0 + s1) + (s2 + s3));                                   \
        }                                                                      \
        unsigned int pb_[8];                                                   \
        _Pragma("unroll")                                                      \
        for (int i_ = 0; i_ < 8; i_++) {                                       \
            PK pk_;                                                            \
            pk_.h = __builtin_amdgcn_cvt_pkrtz(st[2 * i_], st[2 * i_ + 1]);    \
            pb_[i_] = pk_.u;                                                   \
        }                                                                      \
        UB b0_, b1_;                                                           \
        EXCHANGE_P;                                                            \
        ot0 = mfma32(va_[0][0], b0_.v, ot0);                                   \
        ot0 = mfma32(va_[0][1], b1_.v, ot0);                                   \
        ot1 = mfma32(va_[1][0], b0_.v, ot1);                                   \
        ot1 = mfma32(va_[1][1], b1_.v, ot1);                                   \
    }                                                                          \
} while (0)

__global__ __launch_bounds__(128, 4) void k_attn(const float* __restrict__ Q,
                                                 const f16_t* __restrict__ KH,
                                                 const f16_t* __restrict__ VT,
                                                 const unsigned char* __restrict__ BM,
                                                 float* __restrict__ Out) {
    __shared__ float lds_o[64 * 33];
    __shared__ float lds_m[32];
    __shared__ float lds_l[32];

    // R4 mapping: heavy block-rows dispatch first; round-robin XCD dispatch already
    // pins each XCD to 4 fixed bh values.
    const int qi   = 63 - (int)(blockIdx.x >> 5);
    const int bh   = blockIdx.x & 31;
    const int h    = bh & (Hc - 1);
    const int w    = threadIdx.x >> 6;
    const int lane = threadIdx.x & 63;
    const int l31  = lane & 31, hi = lane >> 5;

    const size_t bh_off = (size_t)bh * Sc * Dc;
    const float* q_ptr  = Q  + bh_off;
    const f16_t* khp    = KH + bh_off;
    const f16_t* vtp    = VT + bh_off;

    const int q0   = qi * 32;
    const int brow = qi;
    const unsigned char* bmrow = BM + ((size_t)h * NB + brow) * NB;
    const unsigned long long actmask = __ballot(bmrow[lane] != 0);

    // Q fragments (B-operand of S^T), pre-scaled by log2e for exp2 softmax
    f16x8 qh[4];
    {
        const float* qr = q_ptr + (size_t)(q0 + l31) * Dc + hi * 8;
#pragma unroll
        for (int kc = 0; kc < 4; kc++) {
            f32x4 a = *(const f32x4*)(qr + kc * 16);
            f32x4 b = *(const f32x4*)(qr + kc * 16 + 4);
            float xs[8] = {a[0], a[1], a[2], a[3], b[0], b[1], b[2], b[3]};
#pragma unroll
            for (int j2 = 0; j2 < 8; j2++) qh[kc][j2] = (f16_t)(xs[j2] * LOG2E);
        }
    }

    f32x16 ot0, ot1;
#pragma unroll
    for (int r = 0; r < 16; r++) { ot0[r] = 0.f; ot1[r] = 0.f; }
    float mrow = -INFINITY, lrow = 0.f;

    // this wave handles kb == w (mod 2); single-buffered K (L2-resident)
    for (int ib = w; ib <= brow; ib += 2) {
        STEP(ib);
    }

    // ---- merge the two waves' partials (exact flash-decode merge, log2 domain) ----
    float lsum = xhalf_sum(lrow);
    if (w == 1) {
#pragma unroll
        for (int r = 0; r < 16; r++) {
            int d0 = (r & 3) + 8 * (r >> 2) + 4 * hi;
            lds_o[d0 * 33 + l31]        = ot0[r];
            lds_o[(d0 + 32) * 33 + l31] = ot1[r];
        }
        if (hi == 0) { lds_m[l31] = mrow; lds_l[l31] = lsum; }
    }
    __syncthreads();
    if (w == 0) {
        float m1 = lds_m[l31], l1 = lds_l[l31];
        float mm = fmaxf(mrow, m1);
        float a0 = (mrow > -1e37f) ? fexp2(mrow - mm) : 0.f;
        float a1 = (m1   > -1e37f) ? fexp2(m1   - mm) : 0.f;
        float lt = lsum * a0 + l1 * a1;
        float inv = (lt > 0.f) ? (1.f / lt) : 0.f;
        float* op = Out + bh_off + (size_t)(q0 + l31) * Dc;
#pragma unroll
        for (int g = 0; g < 4; g++) {
            f32x4 w0, w1;
#pragma unroll
            for (int jj = 0; jj < 4; jj++) {
                int r = g * 4 + jj;
                int d0 = jj + 8 * g + 4 * hi;
                w0[jj] = (ot0[r] * a0 + lds_o[d0 * 33 + l31] * a1) * inv;
                w1[jj] = (ot1[r] * a0 + lds_o[(d0 + 32) * 33 + l31] * a1) * inv;
            }
            *(f32x4*)(op + g * 8 + hi * 4)      = w0;
            *(f32x4*)(op + 32 + g * 8 + hi * 4) = w1;
        }
    }
}

extern "C" void kernel_launch(void* const* d_in, const int* in_sizes, int n_in,
                              void* d_out, int out_size, void* d_ws, size_t ws_size,
                              hipStream_t stream) {
    const float* Q    = (const float*)d_in[0];
    const float* K    = (const float*)d_in[1];
    const float* V    = (const float*)d_in[2];
    const float* bias = (const float*)d_in[3];
    const int*   mask = (const int*)d_in[4];
    float* out = (float*)d_out;

    char* ws = (char*)d_ws;
    f16_t* kh = (f16_t*)ws;                                    // 8 MiB
    f16_t* vt = (f16_t*)(ws + QKV_ELEMS * 2);                  // 8 MiB
    unsigned char* bm = (unsigned char*)(ws + QKV_ELEMS * 4);  // 64 KiB

    k_prep <<<4096, 256, 0, stream>>>(K, V, mask, bias, kh, vt, bm);
    k_attn <<<Bc * Hc * NB, 128, 0, stream>>>(Q, kh, vt, bm, out);
}

// Round 13
// 70.062 us; speedup vs baseline: 1.9438x; 1.2352x over previous
//
#include <hip/hip_runtime.h>
#include <hip/hip_bf16.h>

// TritonDynamicAttention: blocksparse causal attention, B=2,H=16,S=2048,D=64, BLOCK=32.
// R13: complementary-pair tiling. WG owns tiles qiA=p and qiB=63-p of one bh: exactly
// 65 steps per pair -> perfect balance, zero tail. Each wave (kv-parity) runs TWO
// independent STEP chains off one shared K/V load (2x ILP, ~26% fewer loads).
// __launch_bounds__(128,2): VGPR<=256, no spill by construction (R12 proved spill was
// the limiter); 2048 waves = 2/SIMD co-resident = 4 chains/SIMD. Epilogue: two-phase
// merge through ONE 8.7KB LDS buffer (3 barriers, epilogue-only).
// Keeps: fp16 carrier, permlane32_swap exchange, exp2 w/ log2e-folded Q, defer-max,
// cvt_pkrtz, early-exit block mask, fused prep.

typedef _Float16 f16_t;
typedef f16_t  f16x8  __attribute__((ext_vector_type(8)));
typedef __fp16 fp16x2 __attribute__((ext_vector_type(2)));
typedef float  f32x4  __attribute__((ext_vector_type(4)));
typedef float  f32x16 __attribute__((ext_vector_type(16)));
typedef int    i32x4  __attribute__((ext_vector_type(4)));
typedef int    i32x2  __attribute__((ext_vector_type(2)));
typedef unsigned int u32x4 __attribute__((ext_vector_type(4)));

constexpr int Bc = 2, Hc = 16, Sc = 2048, Dc = 64;
constexpr int NB = Sc / 32;                              // 64 mask blocks per side
constexpr size_t QKV_ELEMS = (size_t)Bc * Hc * Sc * Dc;  // 4194304
constexpr float LOG2E = 1.4426950408889634f;

__device__ inline f32x16 mfma32(f16x8 a, f16x8 b, f32x16 c) {
    return __builtin_amdgcn_mfma_f32_32x32x16_f16(a, b, c, 0, 0, 0);
}
__device__ inline float fexp2(float x) { return __builtin_amdgcn_exp2f(x); }

union UB { u32x4 u; f16x8 v; };
union PK { fp16x2 h; unsigned int u; };

#if __has_builtin(__builtin_amdgcn_permlane32_swap)
#define HAVE_PLSWAP 1
__device__ inline i32x2 plswap(unsigned int a, unsigned int b) {
    return __builtin_amdgcn_permlane32_swap((int)a, (int)b, false, false);
}
__device__ inline float xhalf_max(float x) {
    i32x2 s = plswap((unsigned int)__float_as_int(x), (unsigned int)__float_as_int(x));
    return fmaxf(__int_as_float(s[0]), __int_as_float(s[1]));
}
__device__ inline float xhalf_sum(float x) {
    i32x2 s = plswap((unsigned int)__float_as_int(x), (unsigned int)__float_as_int(x));
    return __int_as_float(s[0]) + __int_as_float(s[1]);
}
#else
#define HAVE_PLSWAP 0
__device__ inline float xhalf_max(float x) { return fmaxf(x, __shfl_xor(x, 32)); }
__device__ inline float xhalf_sum(float x) { return x + __shfl_xor(x, 32); }
#endif

// ---------- fused prep: [0,2048) K->f16 | [2048,3072) V^T f16 | [3072,4096) blockmask --
__global__ __launch_bounds__(256) void k_prep(const float* __restrict__ K,
                                              const float* __restrict__ V,
                                              const int* __restrict__ mask,
                                              const float* __restrict__ bias,
                                              f16_t* __restrict__ kh,
                                              f16_t* __restrict__ vt,
                                              unsigned char* __restrict__ bm) {
    const int bid = blockIdx.x;
    const int t   = threadIdx.x;
    if (bid < 2048) {
        size_t i = ((size_t)bid * 256 + t) * 8;
        f32x4 a = *(const f32x4*)(K + i);
        f32x4 b = *(const f32x4*)(K + i + 4);
        float xs[8] = {a[0], a[1], a[2], a[3], b[0], b[1], b[2], b[3]};
        f16x8 h;
#pragma unroll
        for (int j = 0; j < 8; j++) h[j] = (f16_t)xs[j];
        *(f16x8*)(kh + i) = h;
    } else if (bid < 3072) {
        __shared__ f16_t tile[64 * 66];
        const int b2 = bid - 2048;
        const int bh = b2 >> 5;
        const int st = b2 & 31;
        {
            int sr = t >> 2, dseg = (t & 3) * 16;
            const float* vr = V + ((size_t)bh * Sc + (size_t)st * 64 + sr) * Dc + dseg;
#pragma unroll
            for (int c = 0; c < 4; c++) {
                f32x4 a = *(const f32x4*)(vr + c * 4);
#pragma unroll
                for (int j = 0; j < 4; j++) tile[sr * 66 + dseg + c * 4 + j] = (f16_t)a[j];
            }
        }
        __syncthreads();
        {
            int dr = t >> 2, sseg = (t & 3) * 16;
            f16x8 h0, h1;
#pragma unroll
            for (int j = 0; j < 8; j++) h0[j] = tile[(sseg + j) * 66 + dr];
#pragma unroll
            for (int j = 0; j < 8; j++) h1[j] = tile[(sseg + 8 + j) * 66 + dr];
            f16_t* outp = vt + ((size_t)bh * Dc + dr) * Sc + (size_t)st * 64 + sseg;
            *(f16x8*)outp = h0;
            *(f16x8*)(outp + 8) = h1;
        }
    } else {
        const int b3 = bid - 3072;
        const int h  = b3 >> 6;
        const int br = b3 & 63;
        float bv = bias[h];
        unsigned char* outp = bm + ((size_t)h * NB + br) * NB;
        if (bv > 0.f) {
            if (t < NB) outp[t] = 1;
            return;
        }
        int bc0 = t >> 3;
        int bc1 = 32 + bc0;
        const int* base = mask + ((size_t)h * Sc + (size_t)br * 32) * (size_t)Sc;
        const int* p0 = base + 4 * t;
        const int* p1 = base + 1024 + 4 * t;
        bool d0 = (bc0 <= br), d1 = (bc1 <= br);
        int acc0 = 0, acc1 = 0;
        if (d0) {
#pragma unroll
            for (int r = 0; r < 4; r++) {
                i32x4 vv = *(const i32x4*)(p0 + (size_t)r * Sc);
                acc0 += vv[0] + vv[1] + vv[2] + vv[3];
            }
        }
        if (d1) {
#pragma unroll
            for (int r = 0; r < 4; r++) {
                i32x4 vv = *(const i32x4*)(p1 + (size_t)r * Sc);
                acc1 += vv[0] + vv[1] + vv[2] + vv[3];
            }
        }
        int g0 = acc0, g1 = acc1;
#pragma unroll
        for (int off = 1; off < 8; off <<= 1) {
            g0 += __shfl_xor(g0, off);
            g1 += __shfl_xor(g1, off);
        }
        bool act0 = (float)g0 + bv > 0.f;   // certified active (remaining rows >= 0)
        bool act1 = (float)g1 + bv > 0.f;
        if (d0 && !act0) {
            for (int r = 4; r < 32; r++) {
                i32x4 vv = *(const i32x4*)(p0 + (size_t)r * Sc);
                acc0 += vv[0] + vv[1] + vv[2] + vv[3];
            }
            int s = acc0;
#pragma unroll
            for (int off = 1; off < 8; off <<= 1) s += __shfl_xor(s, off);
            act0 = (float)s + bv > 0.f;
        }
        if (d1 && !act1) {
            for (int r = 4; r < 32; r++) {
                i32x4 vv = *(const i32x4*)(p1 + (size_t)r * Sc);
                acc1 += vv[0] + vv[1] + vv[2] + vv[3];
            }
            int s = acc1;
#pragma unroll
            for (int off = 1; off < 8; off <<= 1) s += __shfl_xor(s, off);
            act1 = (float)s + bv > 0.f;
        }
        if ((t & 7) == 0) {
            if (d0) outp[bc0] = act0 ? 1 : 0;
            if (d1) outp[bc1] = act1 ? 1 : 0;
        }
    }
}

// ---------- flash blocksparse causal attention: complementary pairs ----------
#if HAVE_PLSWAP
#define EXCHANGE_P do {                                                        \
        i32x2 e0_ = plswap(pb_[0], pb_[2]);                                    \
        i32x2 e1_ = plswap(pb_[1], pb_[3]);                                    \
        i32x2 e2_ = plswap(pb_[4], pb_[6]);                                    \
        i32x2 e3_ = plswap(pb_[5], pb_[7]);                                    \
        b0_.u[0] = (unsigned int)e0_[0]; b0_.u[1] = (unsigned int)e1_[0];      \
        b0_.u[2] = (unsigned int)e0_[1]; b0_.u[3] = (unsigned int)e1_[1];      \
        b1_.u[0] = (unsigned int)e2_[0]; b1_.u[1] = (unsigned int)e3_[0];      \
        b1_.u[2] = (unsigned int)e2_[1]; b1_.u[3] = (unsigned int)e3_[1];      \
} while (0)
#else
#define EXCHANGE_P do {                                                        \
        unsigned int qb_[8];                                                   \
        _Pragma("unroll")                                                      \
        for (int i_ = 0; i_ < 8; i_++)                                         \
            qb_[i_] = (unsigned int)__shfl_xor((int)pb_[i_], 32);              \
        b0_.u[0] = hi ? qb_[2] : pb_[0]; b0_.u[1] = hi ? qb_[3] : pb_[1];      \
        b0_.u[2] = hi ? pb_[2] : qb_[0]; b0_.u[3] = hi ? pb_[3] : qb_[1];      \
        b1_.u[0] = hi ? qb_[6] : pb_[4]; b1_.u[1] = hi ? qb_[7] : pb_[5];      \
        b1_.u[2] = hi ? pb_[6] : qb_[4]; b1_.u[3] = hi ? pb_[7] : qb_[5];      \
} while (0)
#endif

// CORE: one 32x32 tile-step using preloaded kbuf_/va_ (shared between tiles A/B)
#define CORE(OT0, OT1, MR, LR, QH, BROW, kb_) do {                             \
        f32x16 st;                                                             \
        _Pragma("unroll")                                                      \
        for (int r_ = 0; r_ < 16; r_++) st[r_] = 0.f;                          \
        _Pragma("unroll")                                                      \
        for (int kc_ = 0; kc_ < 4; kc_++)                                      \
            st = mfma32(kbuf_[kc_], QH[kc_], st);                              \
        if ((kb_) == (BROW)) {                                                 \
            _Pragma("unroll")                                                  \
            for (int r_ = 0; r_ < 16; r_++) {                                  \
                int kvl_ = (r_ & 3) + 8 * (r_ >> 2) + 4 * hi;                  \
                if (kvl_ > l31) st[r_] = -1e30f;                               \
            }                                                                  \
        }                                                                      \
        float a0_ = fmaxf(fmaxf(st[0], st[1]), st[2]);                         \
        float a1_ = fmaxf(fmaxf(st[3], st[4]), st[5]);                         \
        float a2_ = fmaxf(fmaxf(st[6], st[7]), st[8]);                         \
        float a3_ = fmaxf(fmaxf(st[9], st[10]), st[11]);                       \
        float a4_ = fmaxf(fmaxf(st[12], st[13]), st[14]);                      \
        float b0m_ = fmaxf(fmaxf(a0_, a1_), a2_);                              \
        float b1m_ = fmaxf(fmaxf(a3_, a4_), st[15]);                           \
        float mx_ = xhalf_max(fmaxf(b0m_, b1m_));                              \
        if (__ballot(mx_ > MR + 11.0f)) {                                      \
            float mn_ = fmaxf(MR, mx_);                                        \
            float al_ = fexp2(MR - mn_);                                       \
            MR = mn_;                                                          \
            LR *= al_;                                                         \
            OT0 *= al_; OT1 *= al_;                                            \
        }                                                                      \
        _Pragma("unroll")                                                      \
        for (int r_ = 0; r_ < 16; r_++) st[r_] = fexp2(st[r_] - MR);           \
        {                                                                      \
            float s0 = (st[0] + st[1]) + (st[2] + st[3]);                      \
            float s1 = (st[4] + st[5]) + (st[6] + st[7]);                      \
            float s2 = (st[8] + st[9]) + (st[10] + st[11]);                    \
            float s3 = (st[12] + st[13]) + (st[14] + st[15]);                  \
            LR += ((s0 + s1) + (s2 + s3));                                     \
        }                                                                      \
        unsigned int pb_[8];                                                   \
        _Pragma("unroll")                                                      \
        for (int i_ = 0; i_ < 8; i_++) {                                       \
            PK pk_;                                                            \
            pk_.h = __builtin_amdgcn_cvt_pkrtz(st[2 * i_], st[2 * i_ + 1]);    \
            pb_[i_] = pk_.u;                                                   \
        }                                                                      \
        UB b0_, b1_;                                                           \
        EXCHANGE_P;                                                            \
        OT0 = mfma32(va_[0][0], b0_.v, OT0);                                   \
        OT0 = mfma32(va_[0][1], b1_.v, OT0);                                   \
        OT1 = mfma32(va_[1][0], b0_.v, OT1);                                   \
        OT1 = mfma32(va_[1][1], b1_.v, OT1);                                   \
} while (0)

#define QLOAD(QH, q0_) do {                                                    \
        const float* qr_ = q_ptr + (size_t)((q0_) + l31) * Dc + hi * 8;        \
        _Pragma("unroll")                                                      \
        for (int kc_ = 0; kc_ < 4; kc_++) {                                    \
            f32x4 a_ = *(const f32x4*)(qr_ + kc_ * 16);                        \
            f32x4 b_ = *(const f32x4*)(qr_ + kc_ * 16 + 4);                    \
            float xs_[8] = {a_[0], a_[1], a_[2], a_[3], b_[0], b_[1], b_[2], b_[3]}; \
            _Pragma("unroll")                                                  \
            for (int j_ = 0; j_ < 8; j_++) QH[kc_][j_] = (f16_t)(xs_[j_] * LOG2E); \
        }                                                                      \
} while (0)

#define POST(OT0, OT1, MR, LS) do {                                            \
        _Pragma("unroll")                                                      \
        for (int r_ = 0; r_ < 16; r_++) {                                      \
            int d0_ = (r_ & 3) + 8 * (r_ >> 2) + 4 * hi;                       \
            lds_o[d0_ * 33 + l31]        = OT0[r_];                            \
            lds_o[(d0_ + 32) * 33 + l31] = OT1[r_];                            \
        }                                                                      \
        if (hi == 0) { lds_m[l31] = MR; lds_l[l31] = LS; }                     \
} while (0)

#define MERGE_WRITE(OT0, OT1, MR, LS, q0_) do {                                \
        float m1_ = lds_m[l31], l1_ = lds_l[l31];                              \
        float mm_ = fmaxf(MR, m1_);                                            \
        float c0_ = (MR  > -1e37f) ? fexp2(MR  - mm_) : 0.f;                   \
        float c1_ = (m1_ > -1e37f) ? fexp2(m1_ - mm_) : 0.f;                   \
        float lt_ = LS * c0_ + l1_ * c1_;                                      \
        float inv_ = (lt_ > 0.f) ? (1.f / lt_) : 0.f;                          \
        float* op_ = Out + bh_off + (size_t)((q0_) + l31) * Dc;                \
        _Pragma("unroll")                                                      \
        for (int g_ = 0; g_ < 4; g_++) {                                       \
            f32x4 w0_, w1_;                                                    \
            _Pragma("unroll")                                                  \
            for (int jj_ = 0; jj_ < 4; jj_++) {                                \
                int r_ = g_ * 4 + jj_;                                         \
                int d0_ = jj_ + 8 * g_ + 4 * hi;                               \
                w0_[jj_] = (OT0[r_] * c0_ + lds_o[d0_ * 33 + l31] * c1_) * inv_;        \
                w1_[jj_] = (OT1[r_] * c0_ + lds_o[(d0_ + 32) * 33 + l31] * c1_) * inv_; \
            }                                                                  \
            *(f32x4*)(op_ + g_ * 8 + hi * 4)      = w0_;                       \
            *(f32x4*)(op_ + 32 + g_ * 8 + hi * 4) = w1_;                       \
        }                                                                      \
} while (0)

__global__ __launch_bounds__(128, 2) void k_attn(const float* __restrict__ Q,
                                                 const f16_t* __restrict__ KH,
                                                 const f16_t* __restrict__ VT,
                                                 const unsigned char* __restrict__ BM,
                                                 float* __restrict__ Out) {
    __shared__ float lds_o[64 * 33];
    __shared__ float lds_m[32];
    __shared__ float lds_l[32];

    const int pair = blockIdx.x >> 5;              // 0..31
    const int bh   = blockIdx.x & 31;
    const int h    = bh & (Hc - 1);
    const int w    = threadIdx.x >> 6;
    const int lane = threadIdx.x & 63;
    const int l31  = lane & 31, hi = lane >> 5;

    const size_t bh_off = (size_t)bh * Sc * Dc;
    const float* q_ptr  = Q  + bh_off;
    const f16_t* khp    = KH + bh_off;
    const f16_t* vtp    = VT + bh_off;

    const int qiA = pair, qiB = 63 - pair;         // qiA <= 31 < qiB
    const unsigned char* bmA = BM + ((size_t)h * NB + qiA) * NB;
    const unsigned char* bmB = BM + ((size_t)h * NB + qiB) * NB;
    const unsigned long long amA = __ballot(bmA[lane] != 0);
    const unsigned long long amB = __ballot(bmB[lane] != 0);

    f16x8 qhA[4], qhB[4];
    QLOAD(qhA, qiA * 32);
    QLOAD(qhB, qiB * 32);

    f32x16 oA0, oA1, oB0, oB1;
#pragma unroll
    for (int r = 0; r < 16; r++) { oA0[r] = 0.f; oA1[r] = 0.f; oB0[r] = 0.f; oB1[r] = 0.f; }
    float mA = -INFINITY, lA = 0.f, mB = -INFINITY, lB = 0.f;

    for (int kb = w; kb <= qiB; kb += 2) {
        const bool aA = (kb <= qiA) && ((amA >> kb) & 1ull);
        const bool aB = ((amB >> kb) & 1ull);
        if (!(aA || aB)) continue;
        f16x8 kbuf_[4];
#pragma unroll
        for (int kc = 0; kc < 4; kc++)
            kbuf_[kc] = *(const f16x8*)(khp + (size_t)((kb * 32 + l31) * Dc) + kc * 16 + hi * 8);
        f16x8 va_[2][2];
#pragma unroll
        for (int t = 0; t < 2; t++)
#pragma unroll
            for (int c = 0; c < 2; c++)
                va_[t][c] = *(const f16x8*)(vtp + (size_t)(t * 32 + l31) * Sc + kb * 32 + c * 16 + hi * 8);
        if (aA) CORE(oA0, oA1, mA, lA, qhA, qiA, kb);
        if (aB) CORE(oB0, oB1, mB, lB, qhB, qiB, kb);
    }

    const float lsA = xhalf_sum(lA);
    const float lsB = xhalf_sum(lB);

    // two-phase merge through one LDS buffer (epilogue only)
    if (w == 1) POST(oA0, oA1, mA, lsA);
    __syncthreads();
    if (w == 0) MERGE_WRITE(oA0, oA1, mA, lsA, qiA * 32);
    __syncthreads();
    if (w == 0) POST(oB0, oB1, mB, lsB);
    __syncthreads();
    if (w == 1) MERGE_WRITE(oB0, oB1, mB, lsB, qiB * 32);
}

extern "C" void kernel_launch(void* const* d_in, const int* in_sizes, int n_in,
                              void* d_out, int out_size, void* d_ws, size_t ws_size,
                              hipStream_t stream) {
    const float* Q    = (const float*)d_in[0];
    const float* K    = (const float*)d_in[1];
    const float* V    = (const float*)d_in[2];
    const float* bias = (const float*)d_in[3];
    const int*   mask = (const int*)d_in[4];
    float* out = (float*)d_out;

    char* ws = (char*)d_ws;
    f16_t* kh = (f16_t*)ws;                                    // 8 MiB
    f16_t* vt = (f16_t*)(ws + QKV_ELEMS * 2);                  // 8 MiB
    unsigned char* bm = (unsigned char*)(ws + QKV_ELEMS * 4);  // 64 KiB

    k_prep <<<4096, 256, 0, stream>>>(K, V, mask, bias, kh, vt, bm);
    k_attn <<<Hc * Bc * (NB / 2), 128, 0, stream>>>(Q, kh, vt, bm, out);
}

// Round 14
// 69.658 us; speedup vs baseline: 1.9551x; 1.0058x over previous
//
#include <hip/hip_runtime.h>
#include <hip/hip_bf16.h>

// TritonDynamicAttention: blocksparse causal attention, B=2,H=16,S=2048,D=64, BLOCK=32.
// R14 = R13 + merged dual-CORE: in phase 1 (kb <= qiA) both tiles are (in practice
// always) active -> run BOTH chains in ONE basic block so the compiler interleaves
// them (true ILP-2); R13's if(aA)/if(aB) split them into separate BBs = serial.
// Phase 2 (qiA < kb <= qiB) is B-only. VGPR ~195 < 256 cap of (128,2): no spill.
// Keeps: fp16 carrier, complementary-pair balance (65 steps/WG), shared K/V loads,
// permlane32_swap, exp2 w/ log2e-folded Q, defer-max, cvt_pkrtz, early-exit mask.

typedef _Float16 f16_t;
typedef f16_t  f16x8  __attribute__((ext_vector_type(8)));
typedef __fp16 fp16x2 __attribute__((ext_vector_type(2)));
typedef float  f32x4  __attribute__((ext_vector_type(4)));
typedef float  f32x16 __attribute__((ext_vector_type(16)));
typedef int    i32x4  __attribute__((ext_vector_type(4)));
typedef int    i32x2  __attribute__((ext_vector_type(2)));
typedef unsigned int u32x4 __attribute__((ext_vector_type(4)));

constexpr int Bc = 2, Hc = 16, Sc = 2048, Dc = 64;
constexpr int NB = Sc / 32;                              // 64 mask blocks per side
constexpr size_t QKV_ELEMS = (size_t)Bc * Hc * Sc * Dc;  // 4194304
constexpr float LOG2E = 1.4426950408889634f;

__device__ inline f32x16 mfma32(f16x8 a, f16x8 b, f32x16 c) {
    return __builtin_amdgcn_mfma_f32_32x32x16_f16(a, b, c, 0, 0, 0);
}
__device__ inline float fexp2(float x) { return __builtin_amdgcn_exp2f(x); }

union UB { u32x4 u; f16x8 v; };
union PK { fp16x2 h; unsigned int u; };

#if __has_builtin(__builtin_amdgcn_permlane32_swap)
#define HAVE_PLSWAP 1
__device__ inline i32x2 plswap(unsigned int a, unsigned int b) {
    return __builtin_amdgcn_permlane32_swap((int)a, (int)b, false, false);
}
__device__ inline float xhalf_max(float x) {
    i32x2 s = plswap((unsigned int)__float_as_int(x), (unsigned int)__float_as_int(x));
    return fmaxf(__int_as_float(s[0]), __int_as_float(s[1]));
}
__device__ inline float xhalf_sum(float x) {
    i32x2 s = plswap((unsigned int)__float_as_int(x), (unsigned int)__float_as_int(x));
    return __int_as_float(s[0]) + __int_as_float(s[1]);
}
#else
#define HAVE_PLSWAP 0
__device__ inline float xhalf_max(float x) { return fmaxf(x, __shfl_xor(x, 32)); }
__device__ inline float xhalf_sum(float x) { return x + __shfl_xor(x, 32); }
#endif

// ---------- fused prep: [0,2048) K->f16 | [2048,3072) V^T f16 | [3072,4096) blockmask --
__global__ __launch_bounds__(256) void k_prep(const float* __restrict__ K,
                                              const float* __restrict__ V,
                                              const int* __restrict__ mask,
                                              const float* __restrict__ bias,
                                              f16_t* __restrict__ kh,
                                              f16_t* __restrict__ vt,
                                              unsigned char* __restrict__ bm) {
    const int bid = blockIdx.x;
    const int t   = threadIdx.x;
    if (bid < 2048) {
        size_t i = ((size_t)bid * 256 + t) * 8;
        f32x4 a = *(const f32x4*)(K + i);
        f32x4 b = *(const f32x4*)(K + i + 4);
        float xs[8] = {a[0], a[1], a[2], a[3], b[0], b[1], b[2], b[3]};
        f16x8 h;
#pragma unroll
        for (int j = 0; j < 8; j++) h[j] = (f16_t)xs[j];
        *(f16x8*)(kh + i) = h;
    } else if (bid < 3072) {
        __shared__ f16_t tile[64 * 66];
        const int b2 = bid - 2048;
        const int bh = b2 >> 5;
        const int st = b2 & 31;
        {
            int sr = t >> 2, dseg = (t & 3) * 16;
            const float* vr = V + ((size_t)bh * Sc + (size_t)st * 64 + sr) * Dc + dseg;
#pragma unroll
            for (int c = 0; c < 4; c++) {
                f32x4 a = *(const f32x4*)(vr + c * 4);
#pragma unroll
                for (int j = 0; j < 4; j++) tile[sr * 66 + dseg + c * 4 + j] = (f16_t)a[j];
            }
        }
        __syncthreads();
        {
            int dr = t >> 2, sseg = (t & 3) * 16;
            f16x8 h0, h1;
#pragma unroll
            for (int j = 0; j < 8; j++) h0[j] = tile[(sseg + j) * 66 + dr];
#pragma unroll
            for (int j = 0; j < 8; j++) h1[j] = tile[(sseg + 8 + j) * 66 + dr];
            f16_t* outp = vt + ((size_t)bh * Dc + dr) * Sc + (size_t)st * 64 + sseg;
            *(f16x8*)outp = h0;
            *(f16x8*)(outp + 8) = h1;
        }
    } else {
        const int b3 = bid - 3072;
        const int h  = b3 >> 6;
        const int br = b3 & 63;
        float bv = bias[h];
        unsigned char* outp = bm + ((size_t)h * NB + br) * NB;
        if (bv > 0.f) {
            if (t < NB) outp[t] = 1;
            return;
        }
        int bc0 = t >> 3;
        int bc1 = 32 + bc0;
        const int* base = mask + ((size_t)h * Sc + (size_t)br * 32) * (size_t)Sc;
        const int* p0 = base + 4 * t;
        const int* p1 = base + 1024 + 4 * t;
        bool d0 = (bc0 <= br), d1 = (bc1 <= br);
        int acc0 = 0, acc1 = 0;
        if (d0) {
#pragma unroll
            for (int r = 0; r < 4; r++) {
                i32x4 vv = *(const i32x4*)(p0 + (size_t)r * Sc);
                acc0 += vv[0] + vv[1] + vv[2] + vv[3];
            }
        }
        if (d1) {
#pragma unroll
            for (int r = 0; r < 4; r++) {
                i32x4 vv = *(const i32x4*)(p1 + (size_t)r * Sc);
                acc1 += vv[0] + vv[1] + vv[2] + vv[3];
            }
        }
        int g0 = acc0, g1 = acc1;
#pragma unroll
        for (int off = 1; off < 8; off <<= 1) {
            g0 += __shfl_xor(g0, off);
            g1 += __shfl_xor(g1, off);
        }
        bool act0 = (float)g0 + bv > 0.f;   // certified active (remaining rows >= 0)
        bool act1 = (float)g1 + bv > 0.f;
        if (d0 && !act0) {
            for (int r = 4; r < 32; r++) {
                i32x4 vv = *(const i32x4*)(p0 + (size_t)r * Sc);
                acc0 += vv[0] + vv[1] + vv[2] + vv[3];
            }
            int s = acc0;
#pragma unroll
            for (int off = 1; off < 8; off <<= 1) s += __shfl_xor(s, off);
            act0 = (float)s + bv > 0.f;
        }
        if (d1 && !act1) {
            for (int r = 4; r < 32; r++) {
                i32x4 vv = *(const i32x4*)(p1 + (size_t)r * Sc);
                acc1 += vv[0] + vv[1] + vv[2] + vv[3];
            }
            int s = acc1;
#pragma unroll
            for (int off = 1; off < 8; off <<= 1) s += __shfl_xor(s, off);
            act1 = (float)s + bv > 0.f;
        }
        if ((t & 7) == 0) {
            if (d0) outp[bc0] = act0 ? 1 : 0;
            if (d1) outp[bc1] = act1 ? 1 : 0;
        }
    }
}

// ---------- flash blocksparse causal attention: complementary pairs, dual-CORE -------
#if HAVE_PLSWAP
#define EXCHANGE_P(PB, B0, B1) do {                                            \
        i32x2 e0_ = plswap(PB[0], PB[2]);                                      \
        i32x2 e1_ = plswap(PB[1], PB[3]);                                      \
        i32x2 e2_ = plswap(PB[4], PB[6]);                                      \
        i32x2 e3_ = plswap(PB[5], PB[7]);                                      \
        B0.u[0] = (unsigned int)e0_[0]; B0.u[1] = (unsigned int)e1_[0];        \
        B0.u[2] = (unsigned int)e0_[1]; B0.u[3] = (unsigned int)e1_[1];        \
        B1.u[0] = (unsigned int)e2_[0]; B1.u[1] = (unsigned int)e3_[0];        \
        B1.u[2] = (unsigned int)e2_[1]; B1.u[3] = (unsigned int)e3_[1];        \
} while (0)
#else
#define EXCHANGE_P(PB, B0, B1) do {                                            \
        unsigned int qb_[8];                                                   \
        _Pragma("unroll")                                                      \
        for (int i_ = 0; i_ < 8; i_++)                                         \
            qb_[i_] = (unsigned int)__shfl_xor((int)PB[i_], 32);               \
        B0.u[0] = hi ? qb_[2] : PB[0]; B0.u[1] = hi ? qb_[3] : PB[1];          \
        B0.u[2] = hi ? PB[2] : qb_[0]; B0.u[3] = hi ? PB[3] : qb_[1];          \
        B1.u[0] = hi ? qb_[6] : PB[4]; B1.u[1] = hi ? qb_[7] : PB[5];          \
        B1.u[2] = hi ? PB[6] : qb_[4]; B1.u[3] = hi ? PB[7] : qb_[5];          \
} while (0)
#endif

// softmax tail of one chain, given st filled with scores (modifies st -> p)
#define SMAX_TAIL(ST, OT0, OT1, MR, LR) do {                                   \
        float a0_ = fmaxf(fmaxf(ST[0], ST[1]), ST[2]);                         \
        float a1_ = fmaxf(fmaxf(ST[3], ST[4]), ST[5]);                         \
        float a2_ = fmaxf(fmaxf(ST[6], ST[7]), ST[8]);                         \
        float a3_ = fmaxf(fmaxf(ST[9], ST[10]), ST[11]);                       \
        float a4_ = fmaxf(fmaxf(ST[12], ST[13]), ST[14]);                      \
        float b0m_ = fmaxf(fmaxf(a0_, a1_), a2_);                              \
        float b1m_ = fmaxf(fmaxf(a3_, a4_), ST[15]);                           \
        float mx_ = xhalf_max(fmaxf(b0m_, b1m_));                              \
        if (__ballot(mx_ > MR + 11.0f)) {                                      \
            float mn_ = fmaxf(MR, mx_);                                        \
            float al_ = fexp2(MR - mn_);                                       \
            MR = mn_;                                                          \
            LR *= al_;                                                         \
            OT0 *= al_; OT1 *= al_;                                            \
        }                                                                      \
        _Pragma("unroll")                                                      \
        for (int r_ = 0; r_ < 16; r_++) ST[r_] = fexp2(ST[r_] - MR);           \
        {                                                                      \
            float s0 = (ST[0] + ST[1]) + (ST[2] + ST[3]);                      \
            float s1 = (ST[4] + ST[5]) + (ST[6] + ST[7]);                      \
            float s2 = (ST[8] + ST[9]) + (ST[10] + ST[11]);                    \
            float s3 = (ST[12] + ST[13]) + (ST[14] + ST[15]);                  \
            LR += ((s0 + s1) + (s2 + s3));                                     \
        }                                                                      \
} while (0)

#define PV_STAGE(ST, OT0, OT1) do {                                            \
        unsigned int pb_[8];                                                   \
        _Pragma("unroll")                                                      \
        for (int i_ = 0; i_ < 8; i_++) {                                       \
            PK pk_;                                                            \
            pk_.h = __builtin_amdgcn_cvt_pkrtz(ST[2 * i_], ST[2 * i_ + 1]);    \
            pb_[i_] = pk_.u;                                                   \
        }                                                                      \
        UB b0_, b1_;                                                           \
        EXCHANGE_P(pb_, b0_, b1_);                                             \
        OT0 = mfma32(va_[0][0], b0_.v, OT0);                                   \
        OT0 = mfma32(va_[0][1], b1_.v, OT0);                                   \
        OT1 = mfma32(va_[1][0], b0_.v, OT1);                                   \
        OT1 = mfma32(va_[1][1], b1_.v, OT1);                                   \
} while (0)

#define KV_LOAD(kb_) \
        f16x8 kbuf_[4];                                                        \
        _Pragma("unroll")                                                      \
        for (int kc = 0; kc < 4; kc++)                                         \
            kbuf_[kc] = *(const f16x8*)(khp + (size_t)(((kb_) * 32 + l31) * Dc)\
                                        + kc * 16 + hi * 8);                   \
        f16x8 va_[2][2];                                                       \
        _Pragma("unroll")                                                      \
        for (int t = 0; t < 2; t++)                                            \
            _Pragma("unroll")                                                  \
            for (int c = 0; c < 2; c++)                                        \
                va_[t][c] = *(const f16x8*)(vtp + (size_t)(t * 32 + l31) * Sc  \
                                            + (kb_) * 32 + c * 16 + hi * 8);

// single-tile CORE (fallback / phase 2)
#define CORE(OT0, OT1, MR, LR, QH, BROW, kb_) do {                             \
        f32x16 st;                                                             \
        _Pragma("unroll")                                                      \
        for (int r_ = 0; r_ < 16; r_++) st[r_] = 0.f;                          \
        _Pragma("unroll")                                                      \
        for (int kc_ = 0; kc_ < 4; kc_++)                                      \
            st = mfma32(kbuf_[kc_], QH[kc_], st);                              \
        if ((kb_) == (BROW)) {                                                 \
            _Pragma("unroll")                                                  \
            for (int r_ = 0; r_ < 16; r_++) {                                  \
                int kvl_ = (r_ & 3) + 8 * (r_ >> 2) + 4 * hi;                  \
                if (kvl_ > l31) st[r_] = -1e30f;                               \
            }                                                                  \
        }                                                                      \
        SMAX_TAIL(st, OT0, OT1, MR, LR);                                       \
        PV_STAGE(st, OT0, OT1);                                                \
} while (0)

#define QLOAD(QH, q0_) do {                                                    \
        const float* qr_ = q_ptr + (size_t)((q0_) + l31) * Dc + hi * 8;        \
        _Pragma("unroll")                                                      \
        for (int kc_ = 0; kc_ < 4; kc_++) {                                    \
            f32x4 a_ = *(const f32x4*)(qr_ + kc_ * 16);                        \
            f32x4 b_ = *(const f32x4*)(qr_ + kc_ * 16 + 4);                    \
            float xs_[8] = {a_[0], a_[1], a_[2], a_[3], b_[0], b_[1], b_[2], b_[3]}; \
            _Pragma("unroll")                                                  \
            for (int j_ = 0; j_ < 8; j_++) QH[kc_][j_] = (f16_t)(xs_[j_] * LOG2E); \
        }                                                                      \
} while (0)

#define POST(OT0, OT1, MR, LS) do {                                            \
        _Pragma("unroll")                                                      \
        for (int r_ = 0; r_ < 16; r_++) {                                      \
            int d0_ = (r_ & 3) + 8 * (r_ >> 2) + 4 * hi;                       \
            lds_o[d0_ * 33 + l31]        = OT0[r_];                            \
            lds_o[(d0_ + 32) * 33 + l31] = OT1[r_];                            \
        }                                                                      \
        if (hi == 0) { lds_m[l31] = MR; lds_l[l31] = LS; }                     \
} while (0)

#define MERGE_WRITE(OT0, OT1, MR, LS, q0_) do {                                \
        float m1_ = lds_m[l31], l1_ = lds_l[l31];                              \
        float mm_ = fmaxf(MR, m1_);                                            \
        float c0_ = (MR  > -1e37f) ? fexp2(MR  - mm_) : 0.f;                   \
        float c1_ = (m1_ > -1e37f) ? fexp2(m1_ - mm_) : 0.f;                   \
        float lt_ = LS * c0_ + l1_ * c1_;                                      \
        float inv_ = (lt_ > 0.f) ? (1.f / lt_) : 0.f;                          \
        float* op_ = Out + bh_off + (size_t)((q0_) + l31) * Dc;                \
        _Pragma("unroll")                                                      \
        for (int g_ = 0; g_ < 4; g_++) {                                       \
            f32x4 w0_, w1_;                                                    \
            _Pragma("unroll")                                                  \
            for (int jj_ = 0; jj_ < 4; jj_++) {                                \
                int r_ = g_ * 4 + jj_;                                         \
                int d0_ = jj_ + 8 * g_ + 4 * hi;                               \
                w0_[jj_] = (OT0[r_] * c0_ + lds_o[d0_ * 33 + l31] * c1_) * inv_;        \
                w1_[jj_] = (OT1[r_] * c0_ + lds_o[(d0_ + 32) * 33 + l31] * c1_) * inv_; \
            }                                                                  \
            *(f32x4*)(op_ + g_ * 8 + hi * 4)      = w0_;                       \
            *(f32x4*)(op_ + 32 + g_ * 8 + hi * 4) = w1_;                       \
        }                                                                      \
} while (0)

__global__ __launch_bounds__(128, 2) void k_attn(const float* __restrict__ Q,
                                                 const f16_t* __restrict__ KH,
                                                 const f16_t* __restrict__ VT,
                                                 const unsigned char* __restrict__ BM,
                                                 float* __restrict__ Out) {
    __shared__ float lds_o[64 * 33];
    __shared__ float lds_m[32];
    __shared__ float lds_l[32];

    const int pair = blockIdx.x >> 5;              // 0..31
    const int bh   = blockIdx.x & 31;
    const int h    = bh & (Hc - 1);
    const int w    = threadIdx.x >> 6;
    const int lane = threadIdx.x & 63;
    const int l31  = lane & 31, hi = lane >> 5;

    const size_t bh_off = (size_t)bh * Sc * Dc;
    const float* q_ptr  = Q  + bh_off;
    const f16_t* khp    = KH + bh_off;
    const f16_t* vtp    = VT + bh_off;

    const int qiA = pair, qiB = 63 - pair;         // qiA <= 31 < qiB
    const unsigned char* bmA = BM + ((size_t)h * NB + qiA) * NB;
    const unsigned char* bmB = BM + ((size_t)h * NB + qiB) * NB;
    const unsigned long long amA = __ballot(bmA[lane] != 0);
    const unsigned long long amB = __ballot(bmB[lane] != 0);

    f16x8 qhA[4], qhB[4];
    QLOAD(qhA, qiA * 32);
    QLOAD(qhB, qiB * 32);

    f32x16 oA0, oA1, oB0, oB1;
#pragma unroll
    for (int r = 0; r < 16; r++) { oA0[r] = 0.f; oA1[r] = 0.f; oB0[r] = 0.f; oB1[r] = 0.f; }
    float mA = -INFINITY, lA = 0.f, mB = -INFINITY, lB = 0.f;

    int kb = w;
    // ---- phase 1: kb <= qiA, both tiles in range (both ~always mask-active) ----
    for (; kb <= qiA; kb += 2) {
        const bool aA = (amA >> kb) & 1ull;
        const bool aB = (amB >> kb) & 1ull;
        if (!(aA || aB)) continue;
        KV_LOAD(kb);
        if (aA && aB) {
            // merged dual-CORE: one basic block, compiler interleaves both chains
            f32x16 stA, stB;
#pragma unroll
            for (int r = 0; r < 16; r++) { stA[r] = 0.f; stB[r] = 0.f; }
#pragma unroll
            for (int kc = 0; kc < 4; kc++) {
                stA = mfma32(kbuf_[kc], qhA[kc], stA);
                stB = mfma32(kbuf_[kc], qhB[kc], stB);
            }
            if (kb == qiA) {   // A's diagonal (B's diagonal is in phase 2)
#pragma unroll
                for (int r = 0; r < 16; r++) {
                    int kvl = (r & 3) + 8 * (r >> 2) + 4 * hi;
                    if (kvl > l31) stA[r] = -1e30f;
                }
            }
            SMAX_TAIL(stA, oA0, oA1, mA, lA);
            SMAX_TAIL(stB, oB0, oB1, mB, lB);
            PV_STAGE(stA, oA0, oA1);
            PV_STAGE(stB, oB0, oB1);
        } else if (aA) {
            CORE(oA0, oA1, mA, lA, qhA, qiA, kb);
        } else {
            CORE(oB0, oB1, mB, lB, qhB, qiB, kb);
        }
    }
    // ---- phase 2: qiA < kb <= qiB, tile B only ----
    for (; kb <= qiB; kb += 2) {
        if (!((amB >> kb) & 1ull)) continue;
        KV_LOAD(kb);
        CORE(oB0, oB1, mB, lB, qhB, qiB, kb);
    }

    const float lsA = xhalf_sum(lA);
    const float lsB = xhalf_sum(lB);

    // two-phase merge through one LDS buffer (epilogue only)
    if (w == 1) POST(oA0, oA1, mA, lsA);
    __syncthreads();
    if (w == 0) MERGE_WRITE(oA0, oA1, mA, lsA, qiA * 32);
    __syncthreads();
    if (w == 0) POST(oB0, oB1, mB, lsB);
    __syncthreads();
    if (w == 1) MERGE_WRITE(oB0, oB1, mB, lsB, qiB * 32);
}

extern "C" void kernel_launch(void* const* d_in, const int* in_sizes, int n_in,
                              void* d_out, int out_size, void* d_ws, size_t ws_size,
                              hipStream_t stream) {
    const float* Q    = (const float*)d_in[0];
    const float* K    = (const float*)d_in[1];
    const float* V    = (const float*)d_in[2];
    const float* bias = (const float*)d_in[3];
    const int*   mask = (const int*)d_in[4];
    float* out = (float*)d_out;

    char* ws = (char*)d_ws;
    f16_t* kh = (f16_t*)ws;                                    // 8 MiB
    f16_t* vt = (f16_t*)(ws + QKV_ELEMS * 2);                  // 8 MiB
    unsigned char* bm = (unsigned char*)(ws + QKV_ELEMS * 4);  // 64 KiB

    k_prep <<<4096, 256, 0, stream>>>(K, V, mask, bias, kh, vt, bm);
    k_attn <<<Hc * Bc * (NB / 2), 128, 0, stream>>>(Q, kh, vt, bm, out);
}